// Round 6
// baseline (590.975 us; speedup 1.0000x reference)
//
#include <hip/hip_runtime.h>
#include <hip/hip_bf16.h>
#include <hip/hip_fp16.h>

// Problem constants (fixed by the reference setup)
#define N_VERTS   100000
#define N_HGE     10000
#define N_INC     1600000
#define N_EDGES   1600000
#define C_IN      256
#define C_MID     128
#define C_OUT     64
#define NEG       0.2f

// Radix-partition parameters.
#define EBSHIFT 6
#define NB_E    157              // ceil(10000/64)
#define VBSHIFT 9
#define NB_V    196              // ceil(100000/512)
#define NB_MAX  196
#define PAIRS_PER_BLOCK 4096     // 256 threads x 16
#define QP 16
#define BUCKET_CAP 16384

typedef __attribute__((ext_vector_type(8))) short  bf16x8;
typedef __attribute__((ext_vector_type(4))) float  f32x4;

// Truncation split: v = hi + lo with |err| <~ 2^-16 |v|.
__device__ __forceinline__ void split1(float v, ushort& hi, ushort& lo) {
    const unsigned b = __float_as_uint(v);
    hi = (ushort)(b >> 16);
    const float r = v - __uint_as_float(b & 0xffff0000u);
    lo = (ushort)(__float_as_uint(r) >> 16);
}

// Unpack 4 fp16 (as uint2) and accumulate into float4.
__device__ __forceinline__ void h4acc(float4& a, uint2 p) {
    const __half2 h01 = *(__half2*)&p.x;
    const __half2 h23 = *(__half2*)&p.y;
    const float2 f01 = __half22float2(h01);
    const float2 f23 = __half22float2(h23);
    a.x += f01.x; a.y += f01.y; a.z += f23.x; a.w += f23.y;
}

// Sum float4 across the 4 sub-groups (lanes l, l^16, l^32, l^48).
__device__ __forceinline__ float4 xreduce4(float4 a) {
#pragma unroll
    for (int m = 16; m <= 32; m <<= 1) {
        a.x += __shfl_xor(a.x, m);
        a.y += __shfl_xor(a.y, m);
        a.z += __shfl_xor(a.z, m);
        a.w += __shfl_xor(a.w, m);
    }
    return a;
}

// ---------------------------------------------------------------------------
// One-time weight prep: split W1/W2 into (hi,lo) bf16 and TRANSPOSE to [n][k].
// ---------------------------------------------------------------------------
__global__ __launch_bounds__(256) void
prep_w_kernel(const float* __restrict__ W1, const float* __restrict__ W2,
              ushort* __restrict__ W1t_h, ushort* __restrict__ W1t_l,
              ushort* __restrict__ W2t_h, ushort* __restrict__ W2t_l) {
    const int idx = blockIdx.x * 256 + threadIdx.x;
    if (idx < C_IN * C_MID) {                       // W1t[n][k], n<128,k<256
        const int n = idx >> 8, k = idx & 255;
        ushort hi, lo;
        split1(W1[k * C_MID + n], hi, lo);
        W1t_h[idx] = hi; W1t_l[idx] = lo;
    } else {
        const int j = idx - C_IN * C_MID;
        if (j < C_MID * C_OUT) {                    // W2t[n][k], n<64,k<128
            const int n = j >> 7, k = j & 127;
            ushort hi, lo;
            split1(W2[k * C_OUT + n], hi, lo);
            W2t_h[j] = hi; W2t_l[j] = lo;
        }
    }
}

// ---------------------------------------------------------------------------
// MFMA MLP, low-LDS: h = leaky_relu(x @ W1 + b1) @ W2 + b2, split-bf16.
// 4 waves x 32 rows, two 16-row halves. Layer 1 SWAPPED (A=W1t, B=x):
// x B-frags straight from global (8 consecutive floats/lane), W1t A-frags
// from global (L2-resident). The layer-2 A-frag transpose goes through a
// wave-private 16x132-u32 LDS bounce (hi|lo packed).
// NOTE: the bounce is CROSS-LANE communication — __syncthreads() is REQUIRED
// around it (round-5 lesson: without a fence the compiler may hoist the
// provably-per-lane-disjoint ds_reads above the ds_writes -> garbage/NaN).
// Fragment maps [m89]: A: row=l&15, k=(l>>4)*8+e; B: col=l&15, same k;
// C/D: col=l&15, row=(l>>4)*4+reg.
// ---------------------------------------------------------------------------
#define MBM 128
__global__ __launch_bounds__(256) void
mlp_mfma_kernel(const float* __restrict__ x,
                const ushort* __restrict__ W1t_h, const ushort* __restrict__ W1t_l,
                const ushort* __restrict__ W2t_h, const ushort* __restrict__ W2t_l,
                const float* __restrict__ b1, const float* __restrict__ b2,
                __half* __restrict__ h) {
    __shared__ unsigned tbuf[4][16 * 132];   // 33 KB total, wave-private
    const int t    = threadIdx.x;
    const int lane = t & 63;
    const int w    = t >> 6;
    const int l15  = lane & 15;
    const int lg   = lane >> 4;
    const int rbase = blockIdx.x * MBM + w * 32;
    unsigned* buf = tbuf[w];

    for (int rf = 0; rf < 2; ++rf) {
        const int vrow = rbase + rf * 16 + l15;
        const int srow = vrow < N_VERTS ? vrow : N_VERTS - 1;
        const float* xrow = x + (size_t)srow * C_IN;

        // ---- layer 1 (swapped): D[midcol][row], rows = this 16-row half ----
        f32x4 acc1[8];
#pragma unroll
        for (int i = 0; i < 8; ++i) acc1[i] = (f32x4)0.f;

#pragma unroll
        for (int ks = 0; ks < 8; ++ks) {
            const float4 v0f = *(const float4*)&xrow[ks * 32 + lg * 8];
            const float4 v1f = *(const float4*)&xrow[ks * 32 + lg * 8 + 4];
            union { ushort us[8]; bf16x8 v; } xh, xl;
            split1(v0f.x, xh.us[0], xl.us[0]); split1(v0f.y, xh.us[1], xl.us[1]);
            split1(v0f.z, xh.us[2], xl.us[2]); split1(v0f.w, xh.us[3], xl.us[3]);
            split1(v1f.x, xh.us[4], xl.us[4]); split1(v1f.y, xh.us[5], xl.us[5]);
            split1(v1f.z, xh.us[6], xl.us[6]); split1(v1f.w, xh.us[7], xl.us[7]);
#pragma unroll
            for (int nf = 0; nf < 8; ++nf) {
                const size_t wo = (size_t)(nf * 16 + l15) * C_IN + ks * 32 + lg * 8;
                const bf16x8 wh = *(const bf16x8*)&W1t_h[wo];
                const bf16x8 wl = *(const bf16x8*)&W1t_l[wo];
                acc1[nf] = __builtin_amdgcn_mfma_f32_16x16x32_bf16(wh, xh.v, acc1[nf], 0, 0, 0);
                acc1[nf] = __builtin_amdgcn_mfma_f32_16x16x32_bf16(wl, xh.v, acc1[nf], 0, 0, 0);
                acc1[nf] = __builtin_amdgcn_mfma_f32_16x16x32_bf16(wh, xl.v, acc1[nf], 0, 0, 0);
            }
        }

        // ---- bias + leaky, pack (hi | lo<<16), LDS write ----
        // lane holds (midcol = nf*16+lg*4+jj, row = l15)
#pragma unroll
        for (int nf = 0; nf < 8; ++nf) {
            const float4 bv = *(const float4*)&b1[nf * 16 + lg * 4];
            unsigned pk[4];
#pragma unroll
            for (int jj = 0; jj < 4; ++jj) {
                float v = acc1[nf][jj] + ((const float*)&bv)[jj];
                v = v > 0.f ? v : NEG * v;
                ushort hi, lo; split1(v, hi, lo);
                pk[jj] = (unsigned)hi | ((unsigned)lo << 16);
            }
            *(uint4*)&buf[l15 * 132 + nf * 16 + lg * 4] =
                make_uint4(pk[0], pk[1], pk[2], pk[3]);
        }
        __syncthreads();   // REQUIRED: cross-lane LDS handoff (see header note)

        // ---- layer 2 (standard): A = mid from LDS transpose, B = W2t ----
        f32x4 acc2[4];
#pragma unroll
        for (int i = 0; i < 4; ++i) acc2[i] = (f32x4)0.f;

#pragma unroll
        for (int ks2 = 0; ks2 < 4; ++ks2) {
            const uint4 Ma = *(const uint4*)&buf[l15 * 132 + ks2 * 32 + lg * 8];
            const uint4 Mb = *(const uint4*)&buf[l15 * 132 + ks2 * 32 + lg * 8 + 4];
            union { unsigned u[4]; bf16x8 v; } mh, ml;
            mh.u[0] = (Ma.x & 0xffffu) | (Ma.y << 16);
            ml.u[0] = (Ma.x >> 16)     | (Ma.y & 0xffff0000u);
            mh.u[1] = (Ma.z & 0xffffu) | (Ma.w << 16);
            ml.u[1] = (Ma.z >> 16)     | (Ma.w & 0xffff0000u);
            mh.u[2] = (Mb.x & 0xffffu) | (Mb.y << 16);
            ml.u[2] = (Mb.x >> 16)     | (Mb.y & 0xffff0000u);
            mh.u[3] = (Mb.z & 0xffffu) | (Mb.w << 16);
            ml.u[3] = (Mb.z >> 16)     | (Mb.w & 0xffff0000u);
#pragma unroll
            for (int cf = 0; cf < 4; ++cf) {
                const size_t wo = (size_t)(cf * 16 + l15) * C_MID + ks2 * 32 + lg * 8;
                const bf16x8 wh = *(const bf16x8*)&W2t_h[wo];
                const bf16x8 wl = *(const bf16x8*)&W2t_l[wo];
                acc2[cf] = __builtin_amdgcn_mfma_f32_16x16x32_bf16(mh.v, wh, acc2[cf], 0, 0, 0);
                acc2[cf] = __builtin_amdgcn_mfma_f32_16x16x32_bf16(ml.v, wh, acc2[cf], 0, 0, 0);
                acc2[cf] = __builtin_amdgcn_mfma_f32_16x16x32_bf16(mh.v, wl, acc2[cf], 0, 0, 0);
            }
        }
        __syncthreads();   // protect buf from next rf iteration's writes

        // ---- store h fp16: D2 lane = (row = rf*16+lg*4+jj, col = cf*16+l15)
#pragma unroll
        for (int cf = 0; cf < 4; ++cf) {
            const float b2c = b2[cf * 16 + l15];
#pragma unroll
            for (int jj = 0; jj < 4; ++jj) {
                const int r = rbase + rf * 16 + lg * 4 + jj;
                if (r < N_VERTS)
                    h[(size_t)r * C_OUT + cf * 16 + l15] =
                        __float2half_rn(acc2[cf][jj] + b2c);
            }
        }
    }
}

// ---------------------------------------------------------------------------
// Bucket-granularity count.
// ---------------------------------------------------------------------------
__global__ __launch_bounds__(256) void
bucket_count_kernel(const int* __restrict__ hg_e, const int* __restrict__ hg_v,
                    const int* __restrict__ g_dst,
                    int* __restrict__ bktcnt_e, int* __restrict__ bktcnt_vhg,
                    int* __restrict__ bktcnt_vg) {
    __shared__ int hist[NB_MAX];
    const int t  = threadIdx.x;
    const int i0 = blockIdx.x * PAIRS_PER_BLOCK + t;

    for (int table = 0; table < 3; ++table) {
        const int* dsts; int* bktcnt; int shift, nb;
        if (table == 0)      { dsts = hg_e;  bktcnt = bktcnt_e;   shift = EBSHIFT; nb = NB_E; }
        else if (table == 1) { dsts = hg_v;  bktcnt = bktcnt_vhg; shift = VBSHIFT; nb = NB_V; }
        else                 { dsts = g_dst; bktcnt = bktcnt_vg;  shift = VBSHIFT; nb = NB_V; }

        if (t < nb) hist[t] = 0;
        __syncthreads();
#pragma unroll
        for (int q = 0; q < QP; ++q) {
            const int i = i0 + q * 256;
            if (i < N_INC) atomicAdd(&hist[dsts[i] >> shift], 1);
        }
        __syncthreads();
        if (t < nb) {
            const int c = hist[t];
            if (c) atomicAdd(&bktcnt[t], c);
        }
        __syncthreads();
    }
}

// Three tiny exclusive scans over bucket counts (<=196 each) in one dispatch.
__global__ __launch_bounds__(256) void
bucket_scan_kernel(const int* __restrict__ bktcnt_e,   int* __restrict__ bstart_e,
                   const int* __restrict__ bktcnt_vhg, int* __restrict__ bstart_vhg,
                   const int* __restrict__ bktcnt_vg,  int* __restrict__ bstart_vg) {
    __shared__ int s[256];
    const int* cnt; int* bs; int nb;
    if (blockIdx.x == 0)      { cnt = bktcnt_e;   bs = bstart_e;   nb = NB_E; }
    else if (blockIdx.x == 1) { cnt = bktcnt_vhg; bs = bstart_vhg; nb = NB_V; }
    else                      { cnt = bktcnt_vg;  bs = bstart_vg;  nb = NB_V; }
    const int t = threadIdx.x;
    const int own = (t < nb) ? cnt[t] : 0;
    s[t] = own;
    __syncthreads();
    for (int d = 1; d < 256; d <<= 1) {
        int v = (t >= d) ? s[t - d] : 0;
        __syncthreads();
        s[t] += v;
        __syncthreads();
    }
    if (t < nb) bs[t] = s[t] - own;   // exclusive
}

// ---------------------------------------------------------------------------
// Phase A: radix partition into bucket-dense record runs.
// ---------------------------------------------------------------------------
__global__ __launch_bounds__(256) void
partitionA_kernel(const int* __restrict__ hg_v, const int* __restrict__ hg_e,
                  const int* __restrict__ g_src, const int* __restrict__ g_dst,
                  const int* __restrict__ bstart_e, const int* __restrict__ bstart_vhg,
                  const int* __restrict__ bstart_vg,
                  int* __restrict__ bcur_e, int* __restrict__ bcur_vhg,
                  int* __restrict__ bcur_vg,
                  uint2* __restrict__ rec_e, uint2* __restrict__ rec_vhg,
                  uint2* __restrict__ rec_vg) {
    __shared__ int hist[NB_MAX];
    __shared__ int gb[NB_MAX];
    __shared__ int bb[NB_MAX];
    const int t  = threadIdx.x;
    const int i0 = blockIdx.x * PAIRS_PER_BLOCK + t;

    for (int table = 0; table < 3; ++table) {
        const int *dsts, *pays, *bstart;
        int *bcur; uint2* rec;
        int shift, nb;
        if (table == 0)      { dsts = hg_e;  pays = hg_v;  bstart = bstart_e;
                               bcur = bcur_e;   rec = rec_e;   shift = EBSHIFT; nb = NB_E; }
        else if (table == 1) { dsts = hg_v;  pays = hg_e;  bstart = bstart_vhg;
                               bcur = bcur_vhg; rec = rec_vhg; shift = VBSHIFT; nb = NB_V; }
        else                 { dsts = g_dst; pays = g_src; bstart = bstart_vg;
                               bcur = bcur_vg;  rec = rec_vg;  shift = VBSHIFT; nb = NB_V; }

        if (t < nb) hist[t] = 0;
        __syncthreads();

        int d[QP], p[QP], bk[QP], rk[QP];
#pragma unroll
        for (int q = 0; q < QP; ++q) {
            const int i = i0 + q * 256;
            if (i < N_INC) {
                d[q]  = dsts[i];
                p[q]  = pays[i];
                bk[q] = d[q] >> shift;
                rk[q] = atomicAdd(&hist[bk[q]], 1);
            } else bk[q] = -1;
        }
        __syncthreads();

        if (t < nb) {
            gb[t] = atomicAdd(&bcur[t], hist[t]);
            bb[t] = bstart[t];
        }
        __syncthreads();

#pragma unroll
        for (int q = 0; q < QP; ++q) {
            if (bk[q] >= 0) {
                const int pos = bb[bk[q]] + gb[bk[q]] + rk[q];
                rec[pos] = make_uint2((unsigned)d[q], (unsigned)p[q]);
            }
        }
        __syncthreads();
    }
}

// ---------------------------------------------------------------------------
// Phase B: per-bucket CSR derivation + dense slot build in LDS.
// ---------------------------------------------------------------------------
#define GRID_B (NB_E + 2 * NB_V)
__global__ __launch_bounds__(256) void
partitionB_kernel(const uint2* __restrict__ rec_e, const uint2* __restrict__ rec_vhg,
                  const uint2* __restrict__ rec_vg,
                  const int* __restrict__ bstart_e, const int* __restrict__ bstart_vhg,
                  const int* __restrict__ bstart_vg,
                  int* __restrict__ deg_e, int* __restrict__ deg_vhg,
                  int* __restrict__ deg_vg,
                  int* __restrict__ off_e, int* __restrict__ off_vhg,
                  int* __restrict__ off_vg,
                  int* __restrict__ slot_e, int* __restrict__ slot_vhg,
                  int* __restrict__ slot_vg) {
    __shared__ int slotbuf[BUCKET_CAP];   // 64 KB
    __shared__ int cnt_l[1 << VBSHIFT];   // 2 KB
    __shared__ int cur_l[1 << VBSHIFT];   // 2 KB
    __shared__ int part[256];             // 1 KB

    int blk = blockIdx.x;
    const uint2* rec; const int* bstart; int* deg; int* off; int* slot;
    int b, shift, ndst, nb;
    if (blk < NB_E) {
        rec = rec_e; bstart = bstart_e; deg = deg_e; off = off_e; slot = slot_e;
        shift = EBSHIFT; ndst = N_HGE; nb = NB_E; b = blk;
    } else if (blk < NB_E + NB_V) {
        rec = rec_vhg; bstart = bstart_vhg; deg = deg_vhg; off = off_vhg; slot = slot_vhg;
        shift = VBSHIFT; ndst = N_VERTS; nb = NB_V; b = blk - NB_E;
    } else {
        rec = rec_vg; bstart = bstart_vg; deg = deg_vg; off = off_vg; slot = slot_vg;
        shift = VBSHIFT; ndst = N_VERTS; nb = NB_V; b = blk - NB_E - NB_V;
    }
    const int t    = threadIdx.x;
    const int dlo  = b << shift;
    const int nd   = 1 << shift;
    const int ndc  = min(nd, ndst - dlo);
    const int bs   = bstart[b];
    const int be   = (b == nb - 1) ? N_INC : bstart[b + 1];
    const int bcnt = be - bs;

    for (int j = t; j < nd; j += 256) cnt_l[j] = 0;
    __syncthreads();
    for (int i = bs + t; i < be; i += 256)
        atomicAdd(&cnt_l[(int)rec[i].x - dlo], 1);
    __syncthreads();

    const int chunk = (nd + 255) / 256;     // 1 or 2
    const int lo = t * chunk;
    const int hi = min(lo + chunk, nd);
    int s = 0;
    for (int j = lo; j < hi; ++j) s += cnt_l[j];
    part[t] = s;
    __syncthreads();
    for (int d = 1; d < 256; d <<= 1) {
        int v = (t >= d) ? part[t - d] : 0;
        __syncthreads();
        part[t] += v;
        __syncthreads();
    }
    int run = (t > 0) ? part[t - 1] : 0;
    for (int j = lo; j < hi; ++j) { cur_l[j] = run; run += cnt_l[j]; }
    __syncthreads();

    for (int j = t; j < ndc; j += 256) {
        deg[dlo + j] = cnt_l[j];
        off[dlo + j] = bs + cur_l[j];
    }
    __syncthreads();

    if (bcnt <= BUCKET_CAP) {
        for (int i = bs + t; i < be; i += 256) {
            const uint2 r = rec[i];
            const int lpos = atomicAdd(&cur_l[(int)r.x - dlo], 1);
            slotbuf[lpos] = (int)r.y;
        }
        __syncthreads();
        for (int i = t; i < bcnt; i += 256)
            slot[bs + i] = slotbuf[i];
    } else {
        for (int i = bs + t; i < be; i += 256) {
            const uint2 r = rec[i];
            const int pos = bs + atomicAdd(&cur_l[(int)r.x - dlo], 1);
            slot[pos] = (int)r.y;
        }
    }
}

// ---------------------------------------------------------------------------
// v2e gather: one wave per hyperedge, quad-slot (4 slots/instr, 16 lanes/row,
// 8B half4 loads). sub = lane>>4 picks slot, cp = lane&15 picks channel quad.
// ---------------------------------------------------------------------------
__global__ void gather_e_kernel(const int* __restrict__ slot, const int* __restrict__ off,
                                const int* __restrict__ deg, const __half* __restrict__ h,
                                __half* __restrict__ e_feat) {
    const int wid  = (blockIdx.x * blockDim.x + threadIdx.x) >> 6;
    const int lane = threadIdx.x & 63;
    if (wid >= N_HGE) return;
    const int sub = lane >> 4;
    const int cp  = lane & 15;
    const int n    = deg[wid];
    const int base = off[wid];

    float4 acc = make_float4(0.f, 0.f, 0.f, 0.f);
    int j = 0;
    for (; j + 16 <= n; j += 16) {
#pragma unroll
        for (int q = 0; q < 4; ++q) {
            const int s = slot[base + j + 4 * q + sub];
            h4acc(acc, *(const uint2*)&h[(size_t)s * C_OUT + 4 * cp]);
        }
    }
    for (; j < n; j += 4) {                      // guarded quad tail
        const int idx = j + sub;
        const int s = slot[base + (idx < n ? idx : 0)];
        const uint2 p = *(const uint2*)&h[(size_t)s * C_OUT + 4 * cp];
        if (idx < n) h4acc(acc, p);
    }
    acc = xreduce4(acc);
    const float inv = 1.f / fmaxf((float)n, 1.f);
    if (sub == 0) {
        const __half2 r01 = __float22half2_rn(make_float2(acc.x * inv, acc.y * inv));
        const __half2 r23 = __float22half2_rn(make_float2(acc.z * inv, acc.w * inv));
        uint2 pk;
        pk.x = *(const unsigned*)&r01;
        pk.y = *(const unsigned*)&r23;
        *(uint2*)&e_feat[(size_t)wid * C_OUT + 4 * cp] = pk;
    }
}

// ---------------------------------------------------------------------------
// Fused per-vertex epilogue, quad-slot gathers over e_feat and h.
// ---------------------------------------------------------------------------
__global__ void vertex_out_kernel(const int* __restrict__ slot_vhg,
                                  const int* __restrict__ off_vhg,
                                  const int* __restrict__ deg_vhg,
                                  const int* __restrict__ slot_vg,
                                  const int* __restrict__ off_vg,
                                  const int* __restrict__ deg_vg,
                                  const __half* __restrict__ e_feat,
                                  const __half* __restrict__ h,
                                  const float* __restrict__ w,
                                  float* __restrict__ out) {
    const int wid  = (blockIdx.x * blockDim.x + threadIdx.x) >> 6;
    const int lane = threadIdx.x & 63;
    if (wid >= N_VERTS) return;
    const int sub = lane >> 4;
    const int cp  = lane & 15;

    float4 a_hg = make_float4(0.f, 0.f, 0.f, 0.f);
    float inv_hg;
    {
        const int n = deg_vhg[wid];
        const int base = off_vhg[wid];
        int j = 0;
        for (; j + 16 <= n; j += 16) {
#pragma unroll
            for (int q = 0; q < 4; ++q) {
                const int s = slot_vhg[base + j + 4 * q + sub];
                h4acc(a_hg, *(const uint2*)&e_feat[(size_t)s * C_OUT + 4 * cp]);
            }
        }
        for (; j < n; j += 4) {
            const int idx = j + sub;
            const int s = slot_vhg[base + (idx < n ? idx : 0)];
            const uint2 p = *(const uint2*)&e_feat[(size_t)s * C_OUT + 4 * cp];
            if (idx < n) h4acc(a_hg, p);
        }
        inv_hg = 1.f / fmaxf((float)n, 1.f);
    }

    float4 a_g = make_float4(0.f, 0.f, 0.f, 0.f);
    float inv_g;
    {
        const int n = deg_vg[wid];
        const int base = off_vg[wid];
        int j = 0;
        for (; j + 16 <= n; j += 16) {
#pragma unroll
            for (int q = 0; q < 4; ++q) {
                const int s = slot_vg[base + j + 4 * q + sub];
                h4acc(a_g, *(const uint2*)&h[(size_t)s * C_OUT + 4 * cp]);
            }
        }
        for (; j < n; j += 4) {
            const int idx = j + sub;
            const int s = slot_vg[base + (idx < n ? idx : 0)];
            const uint2 p = *(const uint2*)&h[(size_t)s * C_OUT + 4 * cp];
            if (idx < n) h4acc(a_g, p);
        }
        inv_g = 1.f / fmaxf((float)n, 1.f);
    }

    a_hg = xreduce4(a_hg);
    a_g  = xreduce4(a_g);

    const float w0 = w[0], w1 = w[1];
    const float m  = fmaxf(w0, w1);
    const float e0 = __expf(w0 - m), e1 = __expf(w1 - m);
    const float sw0 = e0 / (e0 + e1), sw1 = e1 / (e0 + e1);
    const float c0 = sw0 * 0.5f;

    float4 hv = make_float4(0.f, 0.f, 0.f, 0.f);
    h4acc(hv, *(const uint2*)&h[(size_t)wid * C_OUT + 4 * cp]);

    float4 o;
    o.x = c0 * (a_g.x * inv_g + a_hg.x * inv_hg) + sw1 * hv.x;
    o.y = c0 * (a_g.y * inv_g + a_hg.y * inv_hg) + sw1 * hv.y;
    o.z = c0 * (a_g.z * inv_g + a_hg.z * inv_hg) + sw1 * hv.z;
    o.w = c0 * (a_g.w * inv_g + a_hg.w * inv_hg) + sw1 * hv.w;
    o.x = o.x > 0.f ? o.x : NEG * o.x;
    o.y = o.y > 0.f ? o.y : NEG * o.y;
    o.z = o.z > 0.f ? o.z : NEG * o.z;
    o.w = o.w > 0.f ? o.w : NEG * o.w;

    if (sub == 0)
        *(float4*)&out[(size_t)wid * C_OUT + 4 * cp] = o;
}

// ---------------------------------------------------------------------------
extern "C" void kernel_launch(void* const* d_in, const int* in_sizes, int n_in,
                              void* d_out, int out_size, void* d_ws, size_t ws_size,
                              hipStream_t stream) {
    const float* x    = (const float*)d_in[0];
    const float* W1   = (const float*)d_in[1];
    const float* b1   = (const float*)d_in[2];
    const float* W2   = (const float*)d_in[3];
    const float* b2   = (const float*)d_in[4];
    const float* w    = (const float*)d_in[5];
    const int*  hg_v  = (const int*)d_in[6];
    const int*  hg_e  = (const int*)d_in[7];
    const int*  g_src = (const int*)d_in[8];
    const int*  g_dst = (const int*)d_in[9];
    float* out = (float*)d_out;

    // ---- workspace layout ----
    // Region R (reused): rec arrays during CSR build, then h/e_feat/Wsplit.
    uint2* rec_e   = (uint2*)d_ws;                 // N_INC   (12.8 MB)
    uint2* rec_vhg = rec_e   + N_INC;              // N_INC   (12.8 MB)
    uint2* rec_vg  = rec_vhg + N_INC;              // N_EDGES (12.8 MB)
    __half* h      = (__half*)d_ws;                // N_VERTS*64 fp16 (12.8 MB)
    __half* e_feat = h + (size_t)N_VERTS * C_OUT;  // N_HGE*64 fp16   (1.28 MB)
    ushort* W1t_h  = (ushort*)(e_feat + (size_t)N_HGE * C_OUT);  // 64 KB
    ushort* W1t_l  = W1t_h + C_IN * C_MID;                       // 64 KB
    ushort* W2t_h  = W1t_l + C_IN * C_MID;                       // 16 KB
    ushort* W2t_l  = W2t_h + C_MID * C_OUT;                      // 16 KB

    int* slot_e    = (int*)(rec_vg + N_EDGES);     // N_INC
    int* slot_vhg  = slot_e   + N_INC;             // N_INC
    int* slot_vg   = slot_vhg + N_INC;             // N_EDGES
    // zeroed int region:
    int* bktcnt_e   = slot_vg  + N_EDGES;          // NB_E
    int* bktcnt_vhg = bktcnt_e   + NB_E;           // NB_V
    int* bktcnt_vg  = bktcnt_vhg + NB_V;           // NB_V
    int* bcur_e     = bktcnt_vg  + NB_V;           // NB_E
    int* bcur_vhg   = bcur_e     + NB_E;           // NB_V
    int* bcur_vg    = bcur_vhg   + NB_V;           // NB_V
    // not zeroed:
    int* bstart_e   = bcur_vg    + NB_V;           // NB_E
    int* bstart_vhg = bstart_e   + NB_E;           // NB_V
    int* bstart_vg  = bstart_vhg + NB_V;           // NB_V
    int* deg_e      = bstart_vg  + NB_V;           // N_HGE
    int* deg_vhg    = deg_e      + N_HGE;          // N_VERTS
    int* deg_vg     = deg_vhg    + N_VERTS;        // N_VERTS
    int* off_e      = deg_vg     + N_VERTS;        // N_HGE
    int* off_vhg    = off_e      + N_HGE;          // N_VERTS
    int* off_vg     = off_vhg    + N_VERTS;        // N_VERTS

    const size_t zero_elems = 2 * ((size_t)NB_E + 2 * (size_t)NB_V);
    hipMemsetAsync(bktcnt_e, 0, zero_elems * sizeof(int), stream);

    // ---- CSR build ----
    const int partA_blocks = (N_INC + PAIRS_PER_BLOCK - 1) / PAIRS_PER_BLOCK;
    bucket_count_kernel<<<partA_blocks, 256, 0, stream>>>(
        hg_e, hg_v, g_dst, bktcnt_e, bktcnt_vhg, bktcnt_vg);
    bucket_scan_kernel<<<3, 256, 0, stream>>>(bktcnt_e, bstart_e,
                                              bktcnt_vhg, bstart_vhg,
                                              bktcnt_vg, bstart_vg);
    partitionA_kernel<<<partA_blocks, 256, 0, stream>>>(
        hg_v, hg_e, g_src, g_dst, bstart_e, bstart_vhg, bstart_vg,
        bcur_e, bcur_vhg, bcur_vg, rec_e, rec_vhg, rec_vg);
    partitionB_kernel<<<GRID_B, 256, 0, stream>>>(
        rec_e, rec_vhg, rec_vg, bstart_e, bstart_vhg, bstart_vg,
        deg_e, deg_vhg, deg_vg, off_e, off_vhg, off_vg,
        slot_e, slot_vhg, slot_vg);

    // ---- weight split (after B: rec region dead) ----
    prep_w_kernel<<<(C_IN * C_MID + C_MID * C_OUT + 255) / 256, 256, 0, stream>>>(
        W1, W2, W1t_h, W1t_l, W2t_h, W2t_l);

    // ---- MFMA MLP (h aliases rec region, fp16 out) ----
    mlp_mfma_kernel<<<(N_VERTS + MBM - 1) / MBM, 256, 0, stream>>>(
        x, W1t_h, W1t_l, W2t_h, W2t_l, b1, b2, h);

    // ---- v2e gather ----
    const int ge_blocks = (int)(((size_t)N_HGE * 64 + 255) / 256);
    gather_e_kernel<<<ge_blocks, 256, 0, stream>>>(slot_e, off_e, deg_e, h, e_feat);

    // ---- fused e2v + graph gather + finalize ----
    const int vo_blocks = (int)(((size_t)N_VERTS * 64 + 255) / 256);
    vertex_out_kernel<<<vo_blocks, 256, 0, stream>>>(slot_vhg, off_vhg, deg_vhg,
                                                     slot_vg, off_vg, deg_vg,
                                                     e_feat, h, w, out);
}

// Round 7
// 464.479 us; speedup vs baseline: 1.2723x; 1.2723x over previous
//
#include <hip/hip_runtime.h>
#include <hip/hip_bf16.h>
#include <hip/hip_fp16.h>

// Problem constants (fixed by the reference setup)
#define N_VERTS   100000
#define N_HGE     10000
#define N_INC     1600000
#define N_EDGES   1600000
#define C_IN      256
#define C_MID     128
#define C_OUT     64
#define NEG       0.2f

// Radix-partition parameters.
#define EBSHIFT 6
#define NB_E    157              // ceil(10000/64)
#define VBSHIFT 9
#define NB_V    196              // ceil(100000/512)
#define NB_MAX  196
#define PAIRS_PER_BLOCK 4096     // 256 threads x 16
#define QP 16
#define BUCKET_CAP 16384

typedef __attribute__((ext_vector_type(8))) short  bf16x8;
typedef __attribute__((ext_vector_type(4))) float  f32x4;

// Truncation split: v = hi + lo with |err| <~ 2^-16 |v|.
__device__ __forceinline__ void split1(float v, ushort& hi, ushort& lo) {
    const unsigned b = __float_as_uint(v);
    hi = (ushort)(b >> 16);
    const float r = v - __uint_as_float(b & 0xffff0000u);
    lo = (ushort)(__float_as_uint(r) >> 16);
}

// Unpack 4 fp16 (as uint2) and accumulate into float4.
__device__ __forceinline__ void h4acc(float4& a, uint2 p) {
    const __half2 h01 = *(__half2*)&p.x;
    const __half2 h23 = *(__half2*)&p.y;
    const float2 f01 = __half22float2(h01);
    const float2 f23 = __half22float2(h23);
    a.x += f01.x; a.y += f01.y; a.z += f23.x; a.w += f23.y;
}

// Sum float4 across the 4 sub-groups (lanes l, l^16, l^32, l^48).
__device__ __forceinline__ float4 xreduce4(float4 a) {
#pragma unroll
    for (int m = 16; m <= 32; m <<= 1) {
        a.x += __shfl_xor(a.x, m);
        a.y += __shfl_xor(a.y, m);
        a.z += __shfl_xor(a.z, m);
        a.w += __shfl_xor(a.w, m);
    }
    return a;
}

// ---------------------------------------------------------------------------
// One-time weight prep: split W1/W2 into (hi,lo) bf16 and TRANSPOSE to [n][k].
// ---------------------------------------------------------------------------
__global__ __launch_bounds__(256) void
prep_w_kernel(const float* __restrict__ W1, const float* __restrict__ W2,
              ushort* __restrict__ W1t_h, ushort* __restrict__ W1t_l,
              ushort* __restrict__ W2t_h, ushort* __restrict__ W2t_l) {
    const int idx = blockIdx.x * 256 + threadIdx.x;
    if (idx < C_IN * C_MID) {                       // W1t[n][k], n<128,k<256
        const int n = idx >> 8, k = idx & 255;
        ushort hi, lo;
        split1(W1[k * C_MID + n], hi, lo);
        W1t_h[idx] = hi; W1t_l[idx] = lo;
    } else {
        const int j = idx - C_IN * C_MID;
        if (j < C_MID * C_OUT) {                    // W2t[n][k], n<64,k<128
            const int n = j >> 7, k = j & 127;
            ushort hi, lo;
            split1(W2[k * C_OUT + n], hi, lo);
            W2t_h[j] = hi; W2t_l[j] = lo;
        }
    }
}

// ---------------------------------------------------------------------------
// MFMA MLP: h = leaky_relu(x @ W1 + b1) @ W2 + b2, split-bf16 (3-term).
// Round-4 proven structure (LDS-staged, coalesced), now with 512 threads:
// 8 waves in a 2x4 grid over the same 128-row tile and 72 KB LDS ->
// 2 blocks/CU x 8 waves = 16 waves/CU (round-4 had 8). Arithmetic identical.
// Fragment maps [m89]: A: row=l&15, k=(l>>4)*8+e; B: col=l&15, same k;
// C/D: col=l&15, row=(l>>4)*4+reg.
// ---------------------------------------------------------------------------
#define MBM 128
__global__ __launch_bounds__(512) void
mlp_mfma_kernel(const float* __restrict__ x,
                const ushort* __restrict__ W1t_h, const ushort* __restrict__ W1t_l,
                const ushort* __restrict__ W2t_h, const ushort* __restrict__ W2t_l,
                const float* __restrict__ b1, const float* __restrict__ b2,
                __half* __restrict__ h) {
    // union LDS: phase1 = xs_h/xs_l/ws_h/ws_l [128][72]; phase2 = mid_h/mid_l [128][136]
    __shared__ ushort buf[36864];                  // 72 KB
    ushort* xs_h = buf;                            // [128][72]
    ushort* xs_l = buf + 9216;
    ushort* ws_h = buf + 18432;                    // [128][72]
    ushort* ws_l = buf + 27648;
    ushort* mid_h = buf;                           // [128][136]
    ushort* mid_l = buf + 17408;

    const int t    = threadIdx.x;
    const int lane = t & 63;
    const int wid  = t >> 6;                       // 0..7
    const int wr   = wid >> 2, wc = wid & 3;       // 2x4 wave grid
    const int v0   = blockIdx.x * MBM;
    const int rem  = N_VERTS - v0;                 // <128 only in last block
    const int l15  = lane & 15;
    const int lg   = lane >> 4;                    // 0..3

    f32x4 acc[4][2];
#pragma unroll
    for (int i = 0; i < 4; ++i) { acc[i][0] = (f32x4)0.f; acc[i][1] = (f32x4)0.f; }

    // ---- layer 1: K tiled by 64 (4 tiles), split-bf16 staged in LDS ----
    for (int kt = 0; kt < 4; ++kt) {
        __syncthreads();
#pragma unroll
        for (int it = 0; it < 4; ++it) {           // x tile: 2048 float4
            const int idx = it * 512 + t;
            const int row = idx >> 4;
            const int c4  = (idx & 15) * 4;
            float4 v = make_float4(0.f, 0.f, 0.f, 0.f);
            if (row < rem)
                v = *(const float4*)&x[(size_t)(v0 + row) * C_IN + kt * 64 + c4];
            ushort h0,h1,h2,h3, l0,l1,l2,l3;
            split1(v.x, h0, l0); split1(v.y, h1, l1);
            split1(v.z, h2, l2); split1(v.w, h3, l3);
            uint2 ph, pl;
            ph.x = (unsigned)h0 | ((unsigned)h1 << 16);
            ph.y = (unsigned)h2 | ((unsigned)h3 << 16);
            pl.x = (unsigned)l0 | ((unsigned)l1 << 16);
            pl.y = (unsigned)l2 | ((unsigned)l3 << 16);
            *(uint2*)&xs_h[row * 72 + c4] = ph;
            *(uint2*)&xs_l[row * 72 + c4] = pl;
        }
#pragma unroll
        for (int it = 0; it < 4; ++it) {           // W1t tile
            const int idx = it * 512 + t;
            const int n  = idx >> 4;
            const int c4 = (idx & 15) * 4;
            *(uint2*)&ws_h[n * 72 + c4] = *(const uint2*)&W1t_h[n * 256 + kt * 64 + c4];
            *(uint2*)&ws_l[n * 72 + c4] = *(const uint2*)&W1t_l[n * 256 + kt * 64 + c4];
        }
        __syncthreads();

#pragma unroll
        for (int ks = 0; ks < 2; ++ks) {
            const int k0 = ks * 32 + lg * 8;
            bf16x8 ah[4], al[4], bh[2], bl[2];
#pragma unroll
            for (int mf = 0; mf < 4; ++mf) {
                const int r = wr * 64 + mf * 16 + l15;
                ah[mf] = *(const bf16x8*)&xs_h[r * 72 + k0];
                al[mf] = *(const bf16x8*)&xs_l[r * 72 + k0];
            }
#pragma unroll
            for (int nf = 0; nf < 2; ++nf) {
                const int n = wc * 32 + nf * 16 + l15;
                bh[nf] = *(const bf16x8*)&ws_h[n * 72 + k0];
                bl[nf] = *(const bf16x8*)&ws_l[n * 72 + k0];
            }
#pragma unroll
            for (int mf = 0; mf < 4; ++mf)
#pragma unroll
                for (int nf = 0; nf < 2; ++nf) {
                    acc[mf][nf] = __builtin_amdgcn_mfma_f32_16x16x32_bf16(
                        ah[mf], bh[nf], acc[mf][nf], 0, 0, 0);
                    acc[mf][nf] = __builtin_amdgcn_mfma_f32_16x16x32_bf16(
                        al[mf], bh[nf], acc[mf][nf], 0, 0, 0);
                    acc[mf][nf] = __builtin_amdgcn_mfma_f32_16x16x32_bf16(
                        ah[mf], bl[nf], acc[mf][nf], 0, 0, 0);
                }
        }
    }
    __syncthreads();

    // ---- bias + leaky, split-write mid[m][k] (k = layer1 col) ----
#pragma unroll
    for (int nf = 0; nf < 2; ++nf) {
        const int col = wc * 32 + nf * 16 + l15;
        const float bias = b1[col];
#pragma unroll
        for (int mf = 0; mf < 4; ++mf)
#pragma unroll
            for (int j = 0; j < 4; ++j) {
                const int r = wr * 64 + mf * 16 + lg * 4 + j;
                float v = acc[mf][nf][j] + bias;
                v = v > 0.f ? v : NEG * v;
                ushort hi, lo;
                split1(v, hi, lo);
                mid_h[r * 136 + col] = hi;
                mid_l[r * 136 + col] = lo;
            }
    }
    __syncthreads();

    // ---- layer 2: K = 128, W2 fragments straight from global (L1-resident) ----
    // wave grid: wr (64-row half) x wc (16-col quarter)
    f32x4 acc2[4];
#pragma unroll
    for (int i = 0; i < 4; ++i) acc2[i] = (f32x4)0.f;

#pragma unroll
    for (int ks2 = 0; ks2 < 4; ++ks2) {
        const int k0 = ks2 * 32 + lg * 8;
        bf16x8 ah[4], al[4];
#pragma unroll
        for (int mf = 0; mf < 4; ++mf) {
            const int r = wr * 64 + mf * 16 + l15;
            ah[mf] = *(const bf16x8*)&mid_h[r * 136 + k0];
            al[mf] = *(const bf16x8*)&mid_l[r * 136 + k0];
        }
        const int n = wc * 16 + l15;
        const bf16x8 bh = *(const bf16x8*)&W2t_h[n * 128 + k0];
        const bf16x8 bl = *(const bf16x8*)&W2t_l[n * 128 + k0];
#pragma unroll
        for (int mf = 0; mf < 4; ++mf) {
            acc2[mf] = __builtin_amdgcn_mfma_f32_16x16x32_bf16(
                ah[mf], bh, acc2[mf], 0, 0, 0);
            acc2[mf] = __builtin_amdgcn_mfma_f32_16x16x32_bf16(
                al[mf], bh, acc2[mf], 0, 0, 0);
            acc2[mf] = __builtin_amdgcn_mfma_f32_16x16x32_bf16(
                ah[mf], bl, acc2[mf], 0, 0, 0);
        }
    }

    // ---- store h as fp16 ----
    {
        const int col = wc * 16 + l15;
        const float b2c = b2[col];
#pragma unroll
        for (int mf = 0; mf < 4; ++mf)
#pragma unroll
            for (int j = 0; j < 4; ++j) {
                const int r = wr * 64 + mf * 16 + lg * 4 + j;
                if (r < rem)
                    h[(size_t)(v0 + r) * C_OUT + col] =
                        __float2half_rn(acc2[mf][j] + b2c);
            }
    }
}

// ---------------------------------------------------------------------------
// Bucket-granularity count.
// ---------------------------------------------------------------------------
__global__ __launch_bounds__(256) void
bucket_count_kernel(const int* __restrict__ hg_e, const int* __restrict__ hg_v,
                    const int* __restrict__ g_dst,
                    int* __restrict__ bktcnt_e, int* __restrict__ bktcnt_vhg,
                    int* __restrict__ bktcnt_vg) {
    __shared__ int hist[NB_MAX];
    const int t  = threadIdx.x;
    const int i0 = blockIdx.x * PAIRS_PER_BLOCK + t;

    for (int table = 0; table < 3; ++table) {
        const int* dsts; int* bktcnt; int shift, nb;
        if (table == 0)      { dsts = hg_e;  bktcnt = bktcnt_e;   shift = EBSHIFT; nb = NB_E; }
        else if (table == 1) { dsts = hg_v;  bktcnt = bktcnt_vhg; shift = VBSHIFT; nb = NB_V; }
        else                 { dsts = g_dst; bktcnt = bktcnt_vg;  shift = VBSHIFT; nb = NB_V; }

        if (t < nb) hist[t] = 0;
        __syncthreads();
#pragma unroll
        for (int q = 0; q < QP; ++q) {
            const int i = i0 + q * 256;
            if (i < N_INC) atomicAdd(&hist[dsts[i] >> shift], 1);
        }
        __syncthreads();
        if (t < nb) {
            const int c = hist[t];
            if (c) atomicAdd(&bktcnt[t], c);
        }
        __syncthreads();
    }
}

// Three tiny exclusive scans over bucket counts (<=196 each) in one dispatch.
__global__ __launch_bounds__(256) void
bucket_scan_kernel(const int* __restrict__ bktcnt_e,   int* __restrict__ bstart_e,
                   const int* __restrict__ bktcnt_vhg, int* __restrict__ bstart_vhg,
                   const int* __restrict__ bktcnt_vg,  int* __restrict__ bstart_vg) {
    __shared__ int s[256];
    const int* cnt; int* bs; int nb;
    if (blockIdx.x == 0)      { cnt = bktcnt_e;   bs = bstart_e;   nb = NB_E; }
    else if (blockIdx.x == 1) { cnt = bktcnt_vhg; bs = bstart_vhg; nb = NB_V; }
    else                      { cnt = bktcnt_vg;  bs = bstart_vg;  nb = NB_V; }
    const int t = threadIdx.x;
    const int own = (t < nb) ? cnt[t] : 0;
    s[t] = own;
    __syncthreads();
    for (int d = 1; d < 256; d <<= 1) {
        int v = (t >= d) ? s[t - d] : 0;
        __syncthreads();
        s[t] += v;
        __syncthreads();
    }
    if (t < nb) bs[t] = s[t] - own;   // exclusive
}

// ---------------------------------------------------------------------------
// Phase A: radix partition into bucket-dense record runs.
// ---------------------------------------------------------------------------
__global__ __launch_bounds__(256) void
partitionA_kernel(const int* __restrict__ hg_v, const int* __restrict__ hg_e,
                  const int* __restrict__ g_src, const int* __restrict__ g_dst,
                  const int* __restrict__ bstart_e, const int* __restrict__ bstart_vhg,
                  const int* __restrict__ bstart_vg,
                  int* __restrict__ bcur_e, int* __restrict__ bcur_vhg,
                  int* __restrict__ bcur_vg,
                  uint2* __restrict__ rec_e, uint2* __restrict__ rec_vhg,
                  uint2* __restrict__ rec_vg) {
    __shared__ int hist[NB_MAX];
    __shared__ int gb[NB_MAX];
    __shared__ int bb[NB_MAX];
    const int t  = threadIdx.x;
    const int i0 = blockIdx.x * PAIRS_PER_BLOCK + t;

    for (int table = 0; table < 3; ++table) {
        const int *dsts, *pays, *bstart;
        int *bcur; uint2* rec;
        int shift, nb;
        if (table == 0)      { dsts = hg_e;  pays = hg_v;  bstart = bstart_e;
                               bcur = bcur_e;   rec = rec_e;   shift = EBSHIFT; nb = NB_E; }
        else if (table == 1) { dsts = hg_v;  pays = hg_e;  bstart = bstart_vhg;
                               bcur = bcur_vhg; rec = rec_vhg; shift = VBSHIFT; nb = NB_V; }
        else                 { dsts = g_dst; pays = g_src; bstart = bstart_vg;
                               bcur = bcur_vg;  rec = rec_vg;  shift = VBSHIFT; nb = NB_V; }

        if (t < nb) hist[t] = 0;
        __syncthreads();

        int d[QP], p[QP], bk[QP], rk[QP];
#pragma unroll
        for (int q = 0; q < QP; ++q) {
            const int i = i0 + q * 256;
            if (i < N_INC) {
                d[q]  = dsts[i];
                p[q]  = pays[i];
                bk[q] = d[q] >> shift;
                rk[q] = atomicAdd(&hist[bk[q]], 1);
            } else bk[q] = -1;
        }
        __syncthreads();

        if (t < nb) {
            gb[t] = atomicAdd(&bcur[t], hist[t]);
            bb[t] = bstart[t];
        }
        __syncthreads();

#pragma unroll
        for (int q = 0; q < QP; ++q) {
            if (bk[q] >= 0) {
                const int pos = bb[bk[q]] + gb[bk[q]] + rk[q];
                rec[pos] = make_uint2((unsigned)d[q], (unsigned)p[q]);
            }
        }
        __syncthreads();
    }
}

// ---------------------------------------------------------------------------
// Phase B: per-bucket CSR derivation + dense slot build in LDS.
// ---------------------------------------------------------------------------
#define GRID_B (NB_E + 2 * NB_V)
__global__ __launch_bounds__(256) void
partitionB_kernel(const uint2* __restrict__ rec_e, const uint2* __restrict__ rec_vhg,
                  const uint2* __restrict__ rec_vg,
                  const int* __restrict__ bstart_e, const int* __restrict__ bstart_vhg,
                  const int* __restrict__ bstart_vg,
                  int* __restrict__ deg_e, int* __restrict__ deg_vhg,
                  int* __restrict__ deg_vg,
                  int* __restrict__ off_e, int* __restrict__ off_vhg,
                  int* __restrict__ off_vg,
                  int* __restrict__ slot_e, int* __restrict__ slot_vhg,
                  int* __restrict__ slot_vg) {
    __shared__ int slotbuf[BUCKET_CAP];   // 64 KB
    __shared__ int cnt_l[1 << VBSHIFT];   // 2 KB
    __shared__ int cur_l[1 << VBSHIFT];   // 2 KB
    __shared__ int part[256];             // 1 KB

    int blk = blockIdx.x;
    const uint2* rec; const int* bstart; int* deg; int* off; int* slot;
    int b, shift, ndst, nb;
    if (blk < NB_E) {
        rec = rec_e; bstart = bstart_e; deg = deg_e; off = off_e; slot = slot_e;
        shift = EBSHIFT; ndst = N_HGE; nb = NB_E; b = blk;
    } else if (blk < NB_E + NB_V) {
        rec = rec_vhg; bstart = bstart_vhg; deg = deg_vhg; off = off_vhg; slot = slot_vhg;
        shift = VBSHIFT; ndst = N_VERTS; nb = NB_V; b = blk - NB_E;
    } else {
        rec = rec_vg; bstart = bstart_vg; deg = deg_vg; off = off_vg; slot = slot_vg;
        shift = VBSHIFT; ndst = N_VERTS; nb = NB_V; b = blk - NB_E - NB_V;
    }
    const int t    = threadIdx.x;
    const int dlo  = b << shift;
    const int nd   = 1 << shift;
    const int ndc  = min(nd, ndst - dlo);
    const int bs   = bstart[b];
    const int be   = (b == nb - 1) ? N_INC : bstart[b + 1];
    const int bcnt = be - bs;

    for (int j = t; j < nd; j += 256) cnt_l[j] = 0;
    __syncthreads();
    for (int i = bs + t; i < be; i += 256)
        atomicAdd(&cnt_l[(int)rec[i].x - dlo], 1);
    __syncthreads();

    const int chunk = (nd + 255) / 256;     // 1 or 2
    const int lo = t * chunk;
    const int hi = min(lo + chunk, nd);
    int s = 0;
    for (int j = lo; j < hi; ++j) s += cnt_l[j];
    part[t] = s;
    __syncthreads();
    for (int d = 1; d < 256; d <<= 1) {
        int v = (t >= d) ? part[t - d] : 0;
        __syncthreads();
        part[t] += v;
        __syncthreads();
    }
    int run = (t > 0) ? part[t - 1] : 0;
    for (int j = lo; j < hi; ++j) { cur_l[j] = run; run += cnt_l[j]; }
    __syncthreads();

    for (int j = t; j < ndc; j += 256) {
        deg[dlo + j] = cnt_l[j];
        off[dlo + j] = bs + cur_l[j];
    }
    __syncthreads();

    if (bcnt <= BUCKET_CAP) {
        for (int i = bs + t; i < be; i += 256) {
            const uint2 r = rec[i];
            const int lpos = atomicAdd(&cur_l[(int)r.x - dlo], 1);
            slotbuf[lpos] = (int)r.y;
        }
        __syncthreads();
        for (int i = t; i < bcnt; i += 256)
            slot[bs + i] = slotbuf[i];
    } else {
        for (int i = bs + t; i < be; i += 256) {
            const uint2 r = rec[i];
            const int pos = bs + atomicAdd(&cur_l[(int)r.x - dlo], 1);
            slot[pos] = (int)r.y;
        }
    }
}

// ---------------------------------------------------------------------------
// v2e gather: one wave per hyperedge, quad-slot (4 slots/instr, 16 lanes/row,
// 8B half4 loads). sub = lane>>4 picks slot, cp = lane&15 picks channel quad.
// ---------------------------------------------------------------------------
__global__ void gather_e_kernel(const int* __restrict__ slot, const int* __restrict__ off,
                                const int* __restrict__ deg, const __half* __restrict__ h,
                                __half* __restrict__ e_feat) {
    const int wid  = (blockIdx.x * blockDim.x + threadIdx.x) >> 6;
    const int lane = threadIdx.x & 63;
    if (wid >= N_HGE) return;
    const int sub = lane >> 4;
    const int cp  = lane & 15;
    const int n    = deg[wid];
    const int base = off[wid];

    float4 acc = make_float4(0.f, 0.f, 0.f, 0.f);
    int j = 0;
    for (; j + 16 <= n; j += 16) {
#pragma unroll
        for (int q = 0; q < 4; ++q) {
            const int s = slot[base + j + 4 * q + sub];
            h4acc(acc, *(const uint2*)&h[(size_t)s * C_OUT + 4 * cp]);
        }
    }
    for (; j < n; j += 4) {                      // guarded quad tail
        const int idx = j + sub;
        const int s = slot[base + (idx < n ? idx : 0)];
        const uint2 p = *(const uint2*)&h[(size_t)s * C_OUT + 4 * cp];
        if (idx < n) h4acc(acc, p);
    }
    acc = xreduce4(acc);
    const float inv = 1.f / fmaxf((float)n, 1.f);
    if (sub == 0) {
        const __half2 r01 = __float22half2_rn(make_float2(acc.x * inv, acc.y * inv));
        const __half2 r23 = __float22half2_rn(make_float2(acc.z * inv, acc.w * inv));
        uint2 pk;
        pk.x = *(const unsigned*)&r01;
        pk.y = *(const unsigned*)&r23;
        *(uint2*)&e_feat[(size_t)wid * C_OUT + 4 * cp] = pk;
    }
}

// ---------------------------------------------------------------------------
// Fused per-vertex epilogue, quad-slot gathers over e_feat and h.
// ---------------------------------------------------------------------------
__global__ void vertex_out_kernel(const int* __restrict__ slot_vhg,
                                  const int* __restrict__ off_vhg,
                                  const int* __restrict__ deg_vhg,
                                  const int* __restrict__ slot_vg,
                                  const int* __restrict__ off_vg,
                                  const int* __restrict__ deg_vg,
                                  const __half* __restrict__ e_feat,
                                  const __half* __restrict__ h,
                                  const float* __restrict__ w,
                                  float* __restrict__ out) {
    const int wid  = (blockIdx.x * blockDim.x + threadIdx.x) >> 6;
    const int lane = threadIdx.x & 63;
    if (wid >= N_VERTS) return;
    const int sub = lane >> 4;
    const int cp  = lane & 15;

    float4 a_hg = make_float4(0.f, 0.f, 0.f, 0.f);
    float inv_hg;
    {
        const int n = deg_vhg[wid];
        const int base = off_vhg[wid];
        int j = 0;
        for (; j + 16 <= n; j += 16) {
#pragma unroll
            for (int q = 0; q < 4; ++q) {
                const int s = slot_vhg[base + j + 4 * q + sub];
                h4acc(a_hg, *(const uint2*)&e_feat[(size_t)s * C_OUT + 4 * cp]);
            }
        }
        for (; j < n; j += 4) {
            const int idx = j + sub;
            const int s = slot_vhg[base + (idx < n ? idx : 0)];
            const uint2 p = *(const uint2*)&e_feat[(size_t)s * C_OUT + 4 * cp];
            if (idx < n) h4acc(a_hg, p);
        }
        inv_hg = 1.f / fmaxf((float)n, 1.f);
    }

    float4 a_g = make_float4(0.f, 0.f, 0.f, 0.f);
    float inv_g;
    {
        const int n = deg_vg[wid];
        const int base = off_vg[wid];
        int j = 0;
        for (; j + 16 <= n; j += 16) {
#pragma unroll
            for (int q = 0; q < 4; ++q) {
                const int s = slot_vg[base + j + 4 * q + sub];
                h4acc(a_g, *(const uint2*)&h[(size_t)s * C_OUT + 4 * cp]);
            }
        }
        for (; j < n; j += 4) {
            const int idx = j + sub;
            const int s = slot_vg[base + (idx < n ? idx : 0)];
            const uint2 p = *(const uint2*)&h[(size_t)s * C_OUT + 4 * cp];
            if (idx < n) h4acc(a_g, p);
        }
        inv_g = 1.f / fmaxf((float)n, 1.f);
    }

    a_hg = xreduce4(a_hg);
    a_g  = xreduce4(a_g);

    const float w0 = w[0], w1 = w[1];
    const float m  = fmaxf(w0, w1);
    const float e0 = __expf(w0 - m), e1 = __expf(w1 - m);
    const float sw0 = e0 / (e0 + e1), sw1 = e1 / (e0 + e1);
    const float c0 = sw0 * 0.5f;

    float4 hv = make_float4(0.f, 0.f, 0.f, 0.f);
    h4acc(hv, *(const uint2*)&h[(size_t)wid * C_OUT + 4 * cp]);

    float4 o;
    o.x = c0 * (a_g.x * inv_g + a_hg.x * inv_hg) + sw1 * hv.x;
    o.y = c0 * (a_g.y * inv_g + a_hg.y * inv_hg) + sw1 * hv.y;
    o.z = c0 * (a_g.z * inv_g + a_hg.z * inv_hg) + sw1 * hv.z;
    o.w = c0 * (a_g.w * inv_g + a_hg.w * inv_hg) + sw1 * hv.w;
    o.x = o.x > 0.f ? o.x : NEG * o.x;
    o.y = o.y > 0.f ? o.y : NEG * o.y;
    o.z = o.z > 0.f ? o.z : NEG * o.z;
    o.w = o.w > 0.f ? o.w : NEG * o.w;

    if (sub == 0)
        *(float4*)&out[(size_t)wid * C_OUT + 4 * cp] = o;
}

// ---------------------------------------------------------------------------
extern "C" void kernel_launch(void* const* d_in, const int* in_sizes, int n_in,
                              void* d_out, int out_size, void* d_ws, size_t ws_size,
                              hipStream_t stream) {
    const float* x    = (const float*)d_in[0];
    const float* W1   = (const float*)d_in[1];
    const float* b1   = (const float*)d_in[2];
    const float* W2   = (const float*)d_in[3];
    const float* b2   = (const float*)d_in[4];
    const float* w    = (const float*)d_in[5];
    const int*  hg_v  = (const int*)d_in[6];
    const int*  hg_e  = (const int*)d_in[7];
    const int*  g_src = (const int*)d_in[8];
    const int*  g_dst = (const int*)d_in[9];
    float* out = (float*)d_out;

    // ---- workspace layout ----
    // Region R (reused): rec arrays during CSR build, then h/e_feat/Wsplit.
    uint2* rec_e   = (uint2*)d_ws;                 // N_INC   (12.8 MB)
    uint2* rec_vhg = rec_e   + N_INC;              // N_INC   (12.8 MB)
    uint2* rec_vg  = rec_vhg + N_INC;              // N_EDGES (12.8 MB)
    __half* h      = (__half*)d_ws;                // N_VERTS*64 fp16 (12.8 MB)
    __half* e_feat = h + (size_t)N_VERTS * C_OUT;  // N_HGE*64 fp16   (1.28 MB)
    ushort* W1t_h  = (ushort*)(e_feat + (size_t)N_HGE * C_OUT);  // 64 KB
    ushort* W1t_l  = W1t_h + C_IN * C_MID;                       // 64 KB
    ushort* W2t_h  = W1t_l + C_IN * C_MID;                       // 16 KB
    ushort* W2t_l  = W2t_h + C_MID * C_OUT;                      // 16 KB

    int* slot_e    = (int*)(rec_vg + N_EDGES);     // N_INC
    int* slot_vhg  = slot_e   + N_INC;             // N_INC
    int* slot_vg   = slot_vhg + N_INC;             // N_EDGES
    // zeroed int region:
    int* bktcnt_e   = slot_vg  + N_EDGES;          // NB_E
    int* bktcnt_vhg = bktcnt_e   + NB_E;           // NB_V
    int* bktcnt_vg  = bktcnt_vhg + NB_V;           // NB_V
    int* bcur_e     = bktcnt_vg  + NB_V;           // NB_E
    int* bcur_vhg   = bcur_e     + NB_E;           // NB_V
    int* bcur_vg    = bcur_vhg   + NB_V;           // NB_V
    // not zeroed:
    int* bstart_e   = bcur_vg    + NB_V;           // NB_E
    int* bstart_vhg = bstart_e   + NB_E;           // NB_V
    int* bstart_vg  = bstart_vhg + NB_V;           // NB_V
    int* deg_e      = bstart_vg  + NB_V;           // N_HGE
    int* deg_vhg    = deg_e      + N_HGE;          // N_VERTS
    int* deg_vg     = deg_vhg    + N_VERTS;        // N_VERTS
    int* off_e      = deg_vg     + N_VERTS;        // N_HGE
    int* off_vhg    = off_e      + N_HGE;          // N_VERTS
    int* off_vg     = off_vhg    + N_VERTS;        // N_VERTS

    const size_t zero_elems = 2 * ((size_t)NB_E + 2 * (size_t)NB_V);
    hipMemsetAsync(bktcnt_e, 0, zero_elems * sizeof(int), stream);

    // ---- CSR build ----
    const int partA_blocks = (N_INC + PAIRS_PER_BLOCK - 1) / PAIRS_PER_BLOCK;
    bucket_count_kernel<<<partA_blocks, 256, 0, stream>>>(
        hg_e, hg_v, g_dst, bktcnt_e, bktcnt_vhg, bktcnt_vg);
    bucket_scan_kernel<<<3, 256, 0, stream>>>(bktcnt_e, bstart_e,
                                              bktcnt_vhg, bstart_vhg,
                                              bktcnt_vg, bstart_vg);
    partitionA_kernel<<<partA_blocks, 256, 0, stream>>>(
        hg_v, hg_e, g_src, g_dst, bstart_e, bstart_vhg, bstart_vg,
        bcur_e, bcur_vhg, bcur_vg, rec_e, rec_vhg, rec_vg);
    partitionB_kernel<<<GRID_B, 256, 0, stream>>>(
        rec_e, rec_vhg, rec_vg, bstart_e, bstart_vhg, bstart_vg,
        deg_e, deg_vhg, deg_vg, off_e, off_vhg, off_vg,
        slot_e, slot_vhg, slot_vg);

    // ---- weight split (after B: rec region dead) ----
    prep_w_kernel<<<(C_IN * C_MID + C_MID * C_OUT + 255) / 256, 256, 0, stream>>>(
        W1, W2, W1t_h, W1t_l, W2t_h, W2t_l);

    // ---- MFMA MLP (h aliases rec region, fp16 out), 512-thread blocks ----
    mlp_mfma_kernel<<<(N_VERTS + MBM - 1) / MBM, 512, 0, stream>>>(
        x, W1t_h, W1t_l, W2t_h, W2t_l, b1, b2, h);

    // ---- v2e gather ----
    const int ge_blocks = (int)(((size_t)N_HGE * 64 + 255) / 256);
    gather_e_kernel<<<ge_blocks, 256, 0, stream>>>(slot_e, off_e, deg_e, h, e_feat);

    // ---- fused e2v + graph gather + finalize ----
    const int vo_blocks = (int)(((size_t)N_VERTS * 64 + 255) / 256);
    vertex_out_kernel<<<vo_blocks, 256, 0, stream>>>(slot_vhg, off_vhg, deg_vhg,
                                                     slot_vg, off_vg, deg_vg,
                                                     e_feat, h, w, out);
}

// Round 8
// 437.984 us; speedup vs baseline: 1.3493x; 1.0605x over previous
//
#include <hip/hip_runtime.h>
#include <hip/hip_bf16.h>
#include <hip/hip_fp16.h>

// Problem constants (fixed by the reference setup)
#define N_VERTS   100000
#define N_HGE     10000
#define N_INC     1600000
#define N_EDGES   1600000
#define C_IN      256
#define C_MID     128
#define C_OUT     64
#define NEG       0.2f

// Radix-partition parameters. Fixed-capacity bucket regions:
//   E-buckets: 64 hyperedges, mean 10240 records, cap 12288 (+20 sigma)
//   V-buckets: 512 vertices,  mean  8192 records, cap 10240 (+22 sigma)
// Caps are statistically unreachable for this fixed input; writes are
// bounds-guarded so even an overflow cannot corrupt memory.
#define EBSHIFT 6
#define NB_E    157              // ceil(10000/64)
#define VBSHIFT 9
#define NB_V    196              // ceil(100000/512)
#define NB_MAX  196
#define ECAP    12288
#define VCAP    10240
#define PAIRS_PER_BLOCK 4096     // 256 threads x 16
#define QP 16

typedef __attribute__((ext_vector_type(8))) short  bf16x8;
typedef __attribute__((ext_vector_type(4))) float  f32x4;

// Truncation split: v = hi + lo with |err| <~ 2^-16 |v|.
__device__ __forceinline__ void split1(float v, ushort& hi, ushort& lo) {
    const unsigned b = __float_as_uint(v);
    hi = (ushort)(b >> 16);
    const float r = v - __uint_as_float(b & 0xffff0000u);
    lo = (ushort)(__float_as_uint(r) >> 16);
}

// Unpack 4 fp16 (as uint2) and accumulate into float4.
__device__ __forceinline__ void h4acc(float4& a, uint2 p) {
    const __half2 h01 = *(__half2*)&p.x;
    const __half2 h23 = *(__half2*)&p.y;
    const float2 f01 = __half22float2(h01);
    const float2 f23 = __half22float2(h23);
    a.x += f01.x; a.y += f01.y; a.z += f23.x; a.w += f23.y;
}

// Sum float4 across the 4 sub-groups (lanes l, l^16, l^32, l^48).
__device__ __forceinline__ float4 xreduce4(float4 a) {
#pragma unroll
    for (int m = 16; m <= 32; m <<= 1) {
        a.x += __shfl_xor(a.x, m);
        a.y += __shfl_xor(a.y, m);
        a.z += __shfl_xor(a.z, m);
        a.w += __shfl_xor(a.w, m);
    }
    return a;
}

// ---------------------------------------------------------------------------
// One-time weight prep: split W1/W2 into (hi,lo) bf16 and TRANSPOSE to [n][k].
// ---------------------------------------------------------------------------
__global__ __launch_bounds__(256) void
prep_w_kernel(const float* __restrict__ W1, const float* __restrict__ W2,
              ushort* __restrict__ W1t_h, ushort* __restrict__ W1t_l,
              ushort* __restrict__ W2t_h, ushort* __restrict__ W2t_l) {
    const int idx = blockIdx.x * 256 + threadIdx.x;
    if (idx < C_IN * C_MID) {                       // W1t[n][k], n<128,k<256
        const int n = idx >> 8, k = idx & 255;
        ushort hi, lo;
        split1(W1[k * C_MID + n], hi, lo);
        W1t_h[idx] = hi; W1t_l[idx] = lo;
    } else {
        const int j = idx - C_IN * C_MID;
        if (j < C_MID * C_OUT) {                    // W2t[n][k], n<64,k<128
            const int n = j >> 7, k = j & 127;
            ushort hi, lo;
            split1(W2[k * C_OUT + n], hi, lo);
            W2t_h[j] = hi; W2t_l[j] = lo;
        }
    }
}

// ---------------------------------------------------------------------------
// MFMA MLP: round-7 proven version (512 threads, 8 waves 2x4, 72 KB LDS).
// ---------------------------------------------------------------------------
#define MBM 128
__global__ __launch_bounds__(512) void
mlp_mfma_kernel(const float* __restrict__ x,
                const ushort* __restrict__ W1t_h, const ushort* __restrict__ W1t_l,
                const ushort* __restrict__ W2t_h, const ushort* __restrict__ W2t_l,
                const float* __restrict__ b1, const float* __restrict__ b2,
                __half* __restrict__ h) {
    // union LDS: phase1 = xs_h/xs_l/ws_h/ws_l [128][72]; phase2 = mid_h/mid_l [128][136]
    __shared__ ushort buf[36864];                  // 72 KB
    ushort* xs_h = buf;                            // [128][72]
    ushort* xs_l = buf + 9216;
    ushort* ws_h = buf + 18432;                    // [128][72]
    ushort* ws_l = buf + 27648;
    ushort* mid_h = buf;                           // [128][136]
    ushort* mid_l = buf + 17408;

    const int t    = threadIdx.x;
    const int lane = t & 63;
    const int wid  = t >> 6;                       // 0..7
    const int wr   = wid >> 2, wc = wid & 3;       // 2x4 wave grid
    const int v0   = blockIdx.x * MBM;
    const int rem  = N_VERTS - v0;                 // <128 only in last block
    const int l15  = lane & 15;
    const int lg   = lane >> 4;                    // 0..3

    f32x4 acc[4][2];
#pragma unroll
    for (int i = 0; i < 4; ++i) { acc[i][0] = (f32x4)0.f; acc[i][1] = (f32x4)0.f; }

    // ---- layer 1: K tiled by 64 (4 tiles), split-bf16 staged in LDS ----
    for (int kt = 0; kt < 4; ++kt) {
        __syncthreads();
#pragma unroll
        for (int it = 0; it < 4; ++it) {           // x tile: 2048 float4
            const int idx = it * 512 + t;
            const int row = idx >> 4;
            const int c4  = (idx & 15) * 4;
            float4 v = make_float4(0.f, 0.f, 0.f, 0.f);
            if (row < rem)
                v = *(const float4*)&x[(size_t)(v0 + row) * C_IN + kt * 64 + c4];
            ushort h0,h1,h2,h3, l0,l1,l2,l3;
            split1(v.x, h0, l0); split1(v.y, h1, l1);
            split1(v.z, h2, l2); split1(v.w, h3, l3);
            uint2 ph, pl;
            ph.x = (unsigned)h0 | ((unsigned)h1 << 16);
            ph.y = (unsigned)h2 | ((unsigned)h3 << 16);
            pl.x = (unsigned)l0 | ((unsigned)l1 << 16);
            pl.y = (unsigned)l2 | ((unsigned)l3 << 16);
            *(uint2*)&xs_h[row * 72 + c4] = ph;
            *(uint2*)&xs_l[row * 72 + c4] = pl;
        }
#pragma unroll
        for (int it = 0; it < 4; ++it) {           // W1t tile
            const int idx = it * 512 + t;
            const int n  = idx >> 4;
            const int c4 = (idx & 15) * 4;
            *(uint2*)&ws_h[n * 72 + c4] = *(const uint2*)&W1t_h[n * 256 + kt * 64 + c4];
            *(uint2*)&ws_l[n * 72 + c4] = *(const uint2*)&W1t_l[n * 256 + kt * 64 + c4];
        }
        __syncthreads();

#pragma unroll
        for (int ks = 0; ks < 2; ++ks) {
            const int k0 = ks * 32 + lg * 8;
            bf16x8 ah[4], al[4], bh[2], bl[2];
#pragma unroll
            for (int mf = 0; mf < 4; ++mf) {
                const int r = wr * 64 + mf * 16 + l15;
                ah[mf] = *(const bf16x8*)&xs_h[r * 72 + k0];
                al[mf] = *(const bf16x8*)&xs_l[r * 72 + k0];
            }
#pragma unroll
            for (int nf = 0; nf < 2; ++nf) {
                const int n = wc * 32 + nf * 16 + l15;
                bh[nf] = *(const bf16x8*)&ws_h[n * 72 + k0];
                bl[nf] = *(const bf16x8*)&ws_l[n * 72 + k0];
            }
#pragma unroll
            for (int mf = 0; mf < 4; ++mf)
#pragma unroll
                for (int nf = 0; nf < 2; ++nf) {
                    acc[mf][nf] = __builtin_amdgcn_mfma_f32_16x16x32_bf16(
                        ah[mf], bh[nf], acc[mf][nf], 0, 0, 0);
                    acc[mf][nf] = __builtin_amdgcn_mfma_f32_16x16x32_bf16(
                        al[mf], bh[nf], acc[mf][nf], 0, 0, 0);
                    acc[mf][nf] = __builtin_amdgcn_mfma_f32_16x16x32_bf16(
                        ah[mf], bl[nf], acc[mf][nf], 0, 0, 0);
                }
        }
    }
    __syncthreads();

    // ---- bias + leaky, split-write mid[m][k] (k = layer1 col) ----
#pragma unroll
    for (int nf = 0; nf < 2; ++nf) {
        const int col = wc * 32 + nf * 16 + l15;
        const float bias = b1[col];
#pragma unroll
        for (int mf = 0; mf < 4; ++mf)
#pragma unroll
            for (int j = 0; j < 4; ++j) {
                const int r = wr * 64 + mf * 16 + lg * 4 + j;
                float v = acc[mf][nf][j] + bias;
                v = v > 0.f ? v : NEG * v;
                ushort hi, lo;
                split1(v, hi, lo);
                mid_h[r * 136 + col] = hi;
                mid_l[r * 136 + col] = lo;
            }
    }
    __syncthreads();

    // ---- layer 2: K = 128, W2 fragments straight from global (L1-resident) ----
    f32x4 acc2[4];
#pragma unroll
    for (int i = 0; i < 4; ++i) acc2[i] = (f32x4)0.f;

#pragma unroll
    for (int ks2 = 0; ks2 < 4; ++ks2) {
        const int k0 = ks2 * 32 + lg * 8;
        bf16x8 ah[4], al[4];
#pragma unroll
        for (int mf = 0; mf < 4; ++mf) {
            const int r = wr * 64 + mf * 16 + l15;
            ah[mf] = *(const bf16x8*)&mid_h[r * 136 + k0];
            al[mf] = *(const bf16x8*)&mid_l[r * 136 + k0];
        }
        const int n = wc * 16 + l15;
        const bf16x8 bh = *(const bf16x8*)&W2t_h[n * 128 + k0];
        const bf16x8 bl = *(const bf16x8*)&W2t_l[n * 128 + k0];
#pragma unroll
        for (int mf = 0; mf < 4; ++mf) {
            acc2[mf] = __builtin_amdgcn_mfma_f32_16x16x32_bf16(
                ah[mf], bh, acc2[mf], 0, 0, 0);
            acc2[mf] = __builtin_amdgcn_mfma_f32_16x16x32_bf16(
                al[mf], bh, acc2[mf], 0, 0, 0);
            acc2[mf] = __builtin_amdgcn_mfma_f32_16x16x32_bf16(
                ah[mf], bl, acc2[mf], 0, 0, 0);
        }
    }

    // ---- store h as fp16 ----
    {
        const int col = wc * 16 + l15;
        const float b2c = b2[col];
#pragma unroll
        for (int mf = 0; mf < 4; ++mf)
#pragma unroll
            for (int j = 0; j < 4; ++j) {
                const int r = wr * 64 + mf * 16 + lg * 4 + j;
                if (r < rem)
                    h[(size_t)(v0 + r) * C_OUT + col] =
                        __float2half_rn(acc2[mf][j] + b2c);
            }
    }
}

// ---------------------------------------------------------------------------
// Phase A: radix partition into fixed-capacity bucket regions.
// Records packed to u32: (dst-in-bucket << 17) | payload.
// LDS-staged: rank per bucket in LDS, reorder, then stream out so each
// (block,bucket) run is CONTIGUOUS in global -> coalesced 4B writes.
// No count/scan prepass needed (bstart = b*CAP compile-time).
// ---------------------------------------------------------------------------
__global__ __launch_bounds__(256) void
partitionA_kernel(const int* __restrict__ hg_v, const int* __restrict__ hg_e,
                  const int* __restrict__ g_src, const int* __restrict__ g_dst,
                  int* __restrict__ bcur_e, int* __restrict__ bcur_vhg,
                  int* __restrict__ bcur_vg,
                  unsigned* __restrict__ rec_e, unsigned* __restrict__ rec_vhg,
                  unsigned* __restrict__ rec_vg) {
    __shared__ int hist[NB_MAX];
    __shared__ int lstart[NB_MAX];
    __shared__ int gb[NB_MAX];
    __shared__ int sscan[256];
    __shared__ unsigned lbuf[PAIRS_PER_BLOCK];        // 16 KB
    __shared__ unsigned char bkt8[PAIRS_PER_BLOCK];   // 4 KB
    const int t    = threadIdx.x;
    const int i0   = blockIdx.x * PAIRS_PER_BLOCK;
    const int vcnt = min(PAIRS_PER_BLOCK, N_INC - i0);

    for (int table = 0; table < 3; ++table) {
        const int *dsts, *pays; int *bcur; unsigned* rec; int shift, nb, cap;
        if (table == 0)      { dsts = hg_e;  pays = hg_v;  bcur = bcur_e;
                               rec = rec_e;   shift = EBSHIFT; nb = NB_E; cap = ECAP; }
        else if (table == 1) { dsts = hg_v;  pays = hg_e;  bcur = bcur_vhg;
                               rec = rec_vhg; shift = VBSHIFT; nb = NB_V; cap = VCAP; }
        else                 { dsts = g_dst; pays = g_src; bcur = bcur_vg;
                               rec = rec_vg;  shift = VBSHIFT; nb = NB_V; cap = VCAP; }
        const int dmask = (1 << shift) - 1;

        if (t < nb) hist[t] = 0;
        __syncthreads();

        unsigned pk[QP]; int bk[QP], rk[QP];
#pragma unroll
        for (int q = 0; q < QP; ++q) {
            const int i = i0 + t + q * 256;
            if (i < N_INC) {
                const int d = dsts[i];
                const int p = pays[i];
                bk[q] = d >> shift;
                pk[q] = ((unsigned)(d & dmask) << 17) | (unsigned)p;
                rk[q] = atomicAdd(&hist[bk[q]], 1);
            } else bk[q] = -1;
        }
        __syncthreads();

        // exclusive scan of hist -> lstart; reserve global runs via bcur
        {
            const int own = (t < nb) ? hist[t] : 0;
            sscan[t] = own;
            __syncthreads();
            for (int d2 = 1; d2 < 256; d2 <<= 1) {
                int v = (t >= d2) ? sscan[t - d2] : 0;
                __syncthreads();
                sscan[t] += v;
                __syncthreads();
            }
            if (t < nb) {
                lstart[t] = sscan[t] - own;
                gb[t] = own ? atomicAdd(&bcur[t], own) : 0;
            }
        }
        __syncthreads();

        // reorder into LDS, bucket-sorted
#pragma unroll
        for (int q = 0; q < QP; ++q) {
            if (bk[q] >= 0) {
                const int lp = lstart[bk[q]] + rk[q];
                lbuf[lp] = pk[q];
                bkt8[lp] = (unsigned char)bk[q];
            }
        }
        __syncthreads();

        // stream out: consecutive lbuf indices within a bucket map to
        // consecutive global addresses (bucket-run coalescing)
        for (int i = t; i < vcnt; i += 256) {
            const int b  = bkt8[i];
            const int pos = gb[b] + (i - lstart[b]);
            if (pos < cap)                         // statistically always true
                rec[(size_t)b * cap + pos] = lbuf[i];
        }
        __syncthreads();   // LDS reused next table
    }
}

// ---------------------------------------------------------------------------
// Phase B: per-bucket CSR derivation + dense slot build in LDS.
// Reads u32 records, derives deg/off, scatters payloads, and overwrites the
// record region IN-PLACE as the final slot array (reads complete before the
// barrier-protected overwrite; buckets are block-disjoint).
// ---------------------------------------------------------------------------
#define GRID_B (NB_E + 2 * NB_V)
__global__ __launch_bounds__(256) void
partitionB_kernel(unsigned* __restrict__ rec_e, unsigned* __restrict__ rec_vhg,
                  unsigned* __restrict__ rec_vg,
                  const int* __restrict__ bcur_e, const int* __restrict__ bcur_vhg,
                  const int* __restrict__ bcur_vg,
                  int* __restrict__ deg_e, int* __restrict__ deg_vhg,
                  int* __restrict__ deg_vg,
                  int* __restrict__ off_e, int* __restrict__ off_vhg,
                  int* __restrict__ off_vg) {
    __shared__ int slotbuf[ECAP];         // 48 KB (ECAP >= VCAP)
    __shared__ int cnt_l[1 << VBSHIFT];   // 2 KB
    __shared__ int cur_l[1 << VBSHIFT];   // 2 KB
    __shared__ int part[256];             // 1 KB

    int blk = blockIdx.x;
    unsigned* rec; const int* bcur; int* deg; int* off;
    int b, shift, ndst, cap;
    if (blk < NB_E) {
        rec = rec_e; bcur = bcur_e; deg = deg_e; off = off_e;
        shift = EBSHIFT; ndst = N_HGE; cap = ECAP; b = blk;
    } else if (blk < NB_E + NB_V) {
        rec = rec_vhg; bcur = bcur_vhg; deg = deg_vhg; off = off_vhg;
        shift = VBSHIFT; ndst = N_VERTS; cap = VCAP; b = blk - NB_E;
    } else {
        rec = rec_vg; bcur = bcur_vg; deg = deg_vg; off = off_vg;
        shift = VBSHIFT; ndst = N_VERTS; cap = VCAP; b = blk - NB_E - NB_V;
    }
    const int t    = threadIdx.x;
    const int dlo  = b << shift;
    const int nd   = 1 << shift;
    const int ndc  = min(nd, ndst - dlo);
    const int bs   = b * cap;
    const int bcnt = min(bcur[b], cap);

    // pass 1: per-dst counts in LDS
    for (int j = t; j < nd; j += 256) cnt_l[j] = 0;
    __syncthreads();
    for (int i = t; i < bcnt; i += 256)
        atomicAdd(&cnt_l[rec[bs + i] >> 17], 1);
    __syncthreads();

    // exclusive scan over nd (64 or 512) counts with 256 threads
    const int chunk = (nd + 255) / 256;     // 1 or 2
    const int lo = t * chunk;
    const int hi = min(lo + chunk, nd);
    int s = 0;
    for (int j = lo; j < hi; ++j) s += cnt_l[j];
    part[t] = s;
    __syncthreads();
    for (int d = 1; d < 256; d <<= 1) {
        int v = (t >= d) ? part[t - d] : 0;
        __syncthreads();
        part[t] += v;
        __syncthreads();
    }
    int run = (t > 0) ? part[t - 1] : 0;
    for (int j = lo; j < hi; ++j) { cur_l[j] = run; run += cnt_l[j]; }
    __syncthreads();

    // emit CSR (deg + global off into the padded slot layout), coalesced
    for (int j = t; j < ndc; j += 256) {
        deg[dlo + j] = cnt_l[j];
        off[dlo + j] = bs + cur_l[j];
    }
    __syncthreads();   // cur_l becomes the scatter cursor below

    // pass 2: scatter payloads into LDS, then overwrite rec in-place as slots
    for (int i = t; i < bcnt; i += 256) {
        const unsigned r = rec[bs + i];
        const int lpos = atomicAdd(&cur_l[r >> 17], 1);
        slotbuf[lpos] = (int)(r & 0x1FFFFu);
    }
    __syncthreads();
    for (int i = t; i < bcnt; i += 256)
        rec[bs + i] = (unsigned)slotbuf[i];
}

// ---------------------------------------------------------------------------
// v2e gather: one wave per hyperedge, quad-slot (4 slots/instr, 16 lanes/row,
// 8B half4 loads). 32-bit offsets for saddr+voffset addressing.
// ---------------------------------------------------------------------------
__global__ void gather_e_kernel(const int* __restrict__ slot, const int* __restrict__ off,
                                const int* __restrict__ deg, const __half* __restrict__ h,
                                __half* __restrict__ e_feat) {
    const int wid  = (blockIdx.x * blockDim.x + threadIdx.x) >> 6;
    const int lane = threadIdx.x & 63;
    if (wid >= N_HGE) return;
    const int sub = lane >> 4;
    const int cp  = lane & 15;
    const int n    = deg[wid];
    const int base = off[wid];

    float4 acc = make_float4(0.f, 0.f, 0.f, 0.f);
    int j = 0;
    for (; j + 16 <= n; j += 16) {
#pragma unroll
        for (int q = 0; q < 4; ++q) {
            const int s = slot[base + j + 4 * q + sub];
            h4acc(acc, *(const uint2*)&h[(unsigned)(s * C_OUT + 4 * cp)]);
        }
    }
    for (; j < n; j += 4) {                      // guarded quad tail
        const int idx = j + sub;
        const int s = slot[base + (idx < n ? idx : 0)];
        const uint2 p = *(const uint2*)&h[(unsigned)(s * C_OUT + 4 * cp)];
        if (idx < n) h4acc(acc, p);
    }
    acc = xreduce4(acc);
    const float inv = 1.f / fmaxf((float)n, 1.f);
    if (sub == 0) {
        const __half2 r01 = __float22half2_rn(make_float2(acc.x * inv, acc.y * inv));
        const __half2 r23 = __float22half2_rn(make_float2(acc.z * inv, acc.w * inv));
        uint2 pk;
        pk.x = *(const unsigned*)&r01;
        pk.y = *(const unsigned*)&r23;
        *(uint2*)&e_feat[(unsigned)(wid * C_OUT + 4 * cp)] = pk;
    }
}

// ---------------------------------------------------------------------------
// Fused per-vertex epilogue, quad-slot gathers over e_feat and h.
// ---------------------------------------------------------------------------
__global__ void vertex_out_kernel(const int* __restrict__ slot_vhg,
                                  const int* __restrict__ off_vhg,
                                  const int* __restrict__ deg_vhg,
                                  const int* __restrict__ slot_vg,
                                  const int* __restrict__ off_vg,
                                  const int* __restrict__ deg_vg,
                                  const __half* __restrict__ e_feat,
                                  const __half* __restrict__ h,
                                  const float* __restrict__ w,
                                  float* __restrict__ out) {
    const int wid  = (blockIdx.x * blockDim.x + threadIdx.x) >> 6;
    const int lane = threadIdx.x & 63;
    if (wid >= N_VERTS) return;
    const int sub = lane >> 4;
    const int cp  = lane & 15;

    float4 a_hg = make_float4(0.f, 0.f, 0.f, 0.f);
    float inv_hg;
    {
        const int n = deg_vhg[wid];
        const int base = off_vhg[wid];
        int j = 0;
        for (; j + 16 <= n; j += 16) {
#pragma unroll
            for (int q = 0; q < 4; ++q) {
                const int s = slot_vhg[base + j + 4 * q + sub];
                h4acc(a_hg, *(const uint2*)&e_feat[(unsigned)(s * C_OUT + 4 * cp)]);
            }
        }
        for (; j < n; j += 4) {
            const int idx = j + sub;
            const int s = slot_vhg[base + (idx < n ? idx : 0)];
            const uint2 p = *(const uint2*)&e_feat[(unsigned)(s * C_OUT + 4 * cp)];
            if (idx < n) h4acc(a_hg, p);
        }
        inv_hg = 1.f / fmaxf((float)n, 1.f);
    }

    float4 a_g = make_float4(0.f, 0.f, 0.f, 0.f);
    float inv_g;
    {
        const int n = deg_vg[wid];
        const int base = off_vg[wid];
        int j = 0;
        for (; j + 16 <= n; j += 16) {
#pragma unroll
            for (int q = 0; q < 4; ++q) {
                const int s = slot_vg[base + j + 4 * q + sub];
                h4acc(a_g, *(const uint2*)&h[(unsigned)(s * C_OUT + 4 * cp)]);
            }
        }
        for (; j < n; j += 4) {
            const int idx = j + sub;
            const int s = slot_vg[base + (idx < n ? idx : 0)];
            const uint2 p = *(const uint2*)&h[(unsigned)(s * C_OUT + 4 * cp)];
            if (idx < n) h4acc(a_g, p);
        }
        inv_g = 1.f / fmaxf((float)n, 1.f);
    }

    a_hg = xreduce4(a_hg);
    a_g  = xreduce4(a_g);

    const float w0 = w[0], w1 = w[1];
    const float m  = fmaxf(w0, w1);
    const float e0 = __expf(w0 - m), e1 = __expf(w1 - m);
    const float sw0 = e0 / (e0 + e1), sw1 = e1 / (e0 + e1);
    const float c0 = sw0 * 0.5f;

    float4 hv = make_float4(0.f, 0.f, 0.f, 0.f);
    h4acc(hv, *(const uint2*)&h[(unsigned)(wid * C_OUT + 4 * cp)]);

    float4 o;
    o.x = c0 * (a_g.x * inv_g + a_hg.x * inv_hg) + sw1 * hv.x;
    o.y = c0 * (a_g.y * inv_g + a_hg.y * inv_hg) + sw1 * hv.y;
    o.z = c0 * (a_g.z * inv_g + a_hg.z * inv_hg) + sw1 * hv.z;
    o.w = c0 * (a_g.w * inv_g + a_hg.w * inv_hg) + sw1 * hv.w;
    o.x = o.x > 0.f ? o.x : NEG * o.x;
    o.y = o.y > 0.f ? o.y : NEG * o.y;
    o.z = o.z > 0.f ? o.z : NEG * o.z;
    o.w = o.w > 0.f ? o.w : NEG * o.w;

    if (sub == 0)
        *(float4*)&out[(unsigned)(wid * C_OUT + 4 * cp)] = o;
}

// ---------------------------------------------------------------------------
extern "C" void kernel_launch(void* const* d_in, const int* in_sizes, int n_in,
                              void* d_out, int out_size, void* d_ws, size_t ws_size,
                              hipStream_t stream) {
    const float* x    = (const float*)d_in[0];
    const float* W1   = (const float*)d_in[1];
    const float* b1   = (const float*)d_in[2];
    const float* W2   = (const float*)d_in[3];
    const float* b2   = (const float*)d_in[4];
    const float* w    = (const float*)d_in[5];
    const int*  hg_v  = (const int*)d_in[6];
    const int*  hg_e  = (const int*)d_in[7];
    const int*  g_src = (const int*)d_in[8];
    const int*  g_dst = (const int*)d_in[9];
    float* out = (float*)d_out;

    // ---- workspace layout (~40 MB total) ----
    // Padded bucket regions double as record storage (phase A/B) and final
    // slot arrays (gathers) — partitionB rewrites them in place.
    unsigned* rec_e   = (unsigned*)d_ws;                       // 157*12288 u32
    unsigned* rec_vhg = rec_e   + (size_t)NB_E * ECAP;         // 196*10240 u32
    unsigned* rec_vg  = rec_vhg + (size_t)NB_V * VCAP;         // 196*10240 u32
    // zeroed int region:
    int* bcur_e    = (int*)(rec_vg + (size_t)NB_V * VCAP);     // NB_E
    int* bcur_vhg  = bcur_e   + NB_E;                          // NB_V
    int* bcur_vg   = bcur_vhg + NB_V;                          // NB_V
    // not zeroed:
    int* deg_e     = bcur_vg  + NB_V;                          // N_HGE
    int* deg_vhg   = deg_e    + N_HGE;                         // N_VERTS
    int* deg_vg    = deg_vhg  + N_VERTS;                       // N_VERTS
    int* off_e     = deg_vg   + N_VERTS;                       // N_HGE
    int* off_vhg   = off_e    + N_HGE;                         // N_VERTS
    int* off_vg    = off_vhg  + N_VERTS;                       // N_VERTS
    __half* h      = (__half*)(off_vg + N_VERTS);              // N_VERTS*64 fp16
    __half* e_feat = h + (size_t)N_VERTS * C_OUT;              // N_HGE*64 fp16
    ushort* W1t_h  = (ushort*)(e_feat + (size_t)N_HGE * C_OUT);
    ushort* W1t_l  = W1t_h + C_IN * C_MID;
    ushort* W2t_h  = W1t_l + C_IN * C_MID;
    ushort* W2t_l  = W2t_h + C_MID * C_OUT;

    hipMemsetAsync(bcur_e, 0, (NB_E + 2 * NB_V) * sizeof(int), stream);

    // ---- partition (no count prepass: fixed-capacity buckets) ----
    const int partA_blocks = (N_INC + PAIRS_PER_BLOCK - 1) / PAIRS_PER_BLOCK;
    partitionA_kernel<<<partA_blocks, 256, 0, stream>>>(
        hg_v, hg_e, g_src, g_dst, bcur_e, bcur_vhg, bcur_vg,
        rec_e, rec_vhg, rec_vg);
    partitionB_kernel<<<GRID_B, 256, 0, stream>>>(
        rec_e, rec_vhg, rec_vg, bcur_e, bcur_vhg, bcur_vg,
        deg_e, deg_vhg, deg_vg, off_e, off_vhg, off_vg);

    // ---- weight split ----
    prep_w_kernel<<<(C_IN * C_MID + C_MID * C_OUT + 255) / 256, 256, 0, stream>>>(
        W1, W2, W1t_h, W1t_l, W2t_h, W2t_l);

    // ---- MFMA MLP (512-thread blocks) ----
    mlp_mfma_kernel<<<(N_VERTS + MBM - 1) / MBM, 512, 0, stream>>>(
        x, W1t_h, W1t_l, W2t_h, W2t_l, b1, b2, h);

    // ---- v2e gather ----
    const int ge_blocks = (int)(((size_t)N_HGE * 64 + 255) / 256);
    gather_e_kernel<<<ge_blocks, 256, 0, stream>>>((const int*)rec_e, off_e, deg_e,
                                                   h, e_feat);

    // ---- fused e2v + graph gather + finalize ----
    const int vo_blocks = (int)(((size_t)N_VERTS * 64 + 255) / 256);
    vertex_out_kernel<<<vo_blocks, 256, 0, stream>>>(
        (const int*)rec_vhg, off_vhg, deg_vhg,
        (const int*)rec_vg,  off_vg,  deg_vg,
        e_feat, h, w, out);
}

// Round 9
// 405.333 us; speedup vs baseline: 1.4580x; 1.0806x over previous
//
#include <hip/hip_runtime.h>
#include <hip/hip_bf16.h>
#include <hip/hip_fp16.h>

// Problem constants (fixed by the reference setup)
#define N_VERTS   100000
#define N_HGE     10000
#define N_INC     1600000
#define N_EDGES   1600000
#define C_IN      256
#define C_MID     128
#define C_OUT     64
#define NEG       0.2f

// Radix-partition parameters. Fixed-capacity bucket regions:
//   E-buckets: 64 hyperedges, mean 10240 records, cap 12288
//   V-buckets: 512 vertices,  mean  8192 records, cap 10240
// Caps are statistically unreachable for this fixed input; writes are
// bounds-guarded so even an overflow cannot corrupt memory.
#define EBSHIFT 6
#define NB_E    157              // ceil(10000/64)
#define VBSHIFT 9
#define NB_V    196              // ceil(100000/512)
#define NB_MAX  196
#define ECAP    12288
#define VCAP    10240
#define PAIRS_PER_BLOCK 4096     // 256 threads x 16
#define QP 16

typedef __attribute__((ext_vector_type(8))) short  bf16x8;
typedef __attribute__((ext_vector_type(4))) float  f32x4;

// Truncation split: v = hi + lo with |err| <~ 2^-16 |v|.
__device__ __forceinline__ void split1(float v, ushort& hi, ushort& lo) {
    const unsigned b = __float_as_uint(v);
    hi = (ushort)(b >> 16);
    const float r = v - __uint_as_float(b & 0xffff0000u);
    lo = (ushort)(__float_as_uint(r) >> 16);
}

// Unpack 8 fp16 (as uint4) and accumulate into two float4s.
__device__ __forceinline__ void h8acc(float4& a0, float4& a1, uint4 p) {
    const float2 f0 = __half22float2(*(__half2*)&p.x);
    const float2 f1 = __half22float2(*(__half2*)&p.y);
    const float2 f2 = __half22float2(*(__half2*)&p.z);
    const float2 f3 = __half22float2(*(__half2*)&p.w);
    a0.x += f0.x; a0.y += f0.y; a0.z += f1.x; a0.w += f1.y;
    a1.x += f2.x; a1.y += f2.y; a1.z += f3.x; a1.w += f3.y;
}

// Sum 8 floats across the 8 sub-groups (lanes l, l^8, l^16, ..., l^56).
__device__ __forceinline__ void xreduce8(float4& a, float4& b) {
#pragma unroll
    for (int m = 8; m <= 32; m <<= 1) {
        a.x += __shfl_xor(a.x, m); a.y += __shfl_xor(a.y, m);
        a.z += __shfl_xor(a.z, m); a.w += __shfl_xor(a.w, m);
        b.x += __shfl_xor(b.x, m); b.y += __shfl_xor(b.y, m);
        b.z += __shfl_xor(b.z, m); b.w += __shfl_xor(b.w, m);
    }
}

// ---------------------------------------------------------------------------
// One-time weight prep: split W1/W2 into (hi,lo) bf16 and TRANSPOSE to [n][k].
// ---------------------------------------------------------------------------
__global__ __launch_bounds__(256) void
prep_w_kernel(const float* __restrict__ W1, const float* __restrict__ W2,
              ushort* __restrict__ W1t_h, ushort* __restrict__ W1t_l,
              ushort* __restrict__ W2t_h, ushort* __restrict__ W2t_l) {
    const int idx = blockIdx.x * 256 + threadIdx.x;
    if (idx < C_IN * C_MID) {                       // W1t[n][k], n<128,k<256
        const int n = idx >> 8, k = idx & 255;
        ushort hi, lo;
        split1(W1[k * C_MID + n], hi, lo);
        W1t_h[idx] = hi; W1t_l[idx] = lo;
    } else {
        const int j = idx - C_IN * C_MID;
        if (j < C_MID * C_OUT) {                    // W2t[n][k], n<64,k<128
            const int n = j >> 7, k = j & 127;
            ushort hi, lo;
            split1(W2[k * C_OUT + n], hi, lo);
            W2t_h[j] = hi; W2t_l[j] = lo;
        }
    }
}

// ---------------------------------------------------------------------------
// MFMA MLP: round-7 proven version (512 threads, 8 waves 2x4, 72 KB LDS).
// ---------------------------------------------------------------------------
#define MBM 128
__global__ __launch_bounds__(512) void
mlp_mfma_kernel(const float* __restrict__ x,
                const ushort* __restrict__ W1t_h, const ushort* __restrict__ W1t_l,
                const ushort* __restrict__ W2t_h, const ushort* __restrict__ W2t_l,
                const float* __restrict__ b1, const float* __restrict__ b2,
                __half* __restrict__ h) {
    // union LDS: phase1 = xs_h/xs_l/ws_h/ws_l [128][72]; phase2 = mid_h/mid_l [128][136]
    __shared__ ushort buf[36864];                  // 72 KB
    ushort* xs_h = buf;                            // [128][72]
    ushort* xs_l = buf + 9216;
    ushort* ws_h = buf + 18432;                    // [128][72]
    ushort* ws_l = buf + 27648;
    ushort* mid_h = buf;                           // [128][136]
    ushort* mid_l = buf + 17408;

    const int t    = threadIdx.x;
    const int lane = t & 63;
    const int wid  = t >> 6;                       // 0..7
    const int wr   = wid >> 2, wc = wid & 3;       // 2x4 wave grid
    const int v0   = blockIdx.x * MBM;
    const int rem  = N_VERTS - v0;                 // <128 only in last block
    const int l15  = lane & 15;
    const int lg   = lane >> 4;                    // 0..3

    f32x4 acc[4][2];
#pragma unroll
    for (int i = 0; i < 4; ++i) { acc[i][0] = (f32x4)0.f; acc[i][1] = (f32x4)0.f; }

    // ---- layer 1: K tiled by 64 (4 tiles), split-bf16 staged in LDS ----
    for (int kt = 0; kt < 4; ++kt) {
        __syncthreads();
#pragma unroll
        for (int it = 0; it < 4; ++it) {           // x tile: 2048 float4
            const int idx = it * 512 + t;
            const int row = idx >> 4;
            const int c4  = (idx & 15) * 4;
            float4 v = make_float4(0.f, 0.f, 0.f, 0.f);
            if (row < rem)
                v = *(const float4*)&x[(size_t)(v0 + row) * C_IN + kt * 64 + c4];
            ushort h0,h1,h2,h3, l0,l1,l2,l3;
            split1(v.x, h0, l0); split1(v.y, h1, l1);
            split1(v.z, h2, l2); split1(v.w, h3, l3);
            uint2 ph, pl;
            ph.x = (unsigned)h0 | ((unsigned)h1 << 16);
            ph.y = (unsigned)h2 | ((unsigned)h3 << 16);
            pl.x = (unsigned)l0 | ((unsigned)l1 << 16);
            pl.y = (unsigned)l2 | ((unsigned)l3 << 16);
            *(uint2*)&xs_h[row * 72 + c4] = ph;
            *(uint2*)&xs_l[row * 72 + c4] = pl;
        }
#pragma unroll
        for (int it = 0; it < 4; ++it) {           // W1t tile
            const int idx = it * 512 + t;
            const int n  = idx >> 4;
            const int c4 = (idx & 15) * 4;
            *(uint2*)&ws_h[n * 72 + c4] = *(const uint2*)&W1t_h[n * 256 + kt * 64 + c4];
            *(uint2*)&ws_l[n * 72 + c4] = *(const uint2*)&W1t_l[n * 256 + kt * 64 + c4];
        }
        __syncthreads();

#pragma unroll
        for (int ks = 0; ks < 2; ++ks) {
            const int k0 = ks * 32 + lg * 8;
            bf16x8 ah[4], al[4], bh[2], bl[2];
#pragma unroll
            for (int mf = 0; mf < 4; ++mf) {
                const int r = wr * 64 + mf * 16 + l15;
                ah[mf] = *(const bf16x8*)&xs_h[r * 72 + k0];
                al[mf] = *(const bf16x8*)&xs_l[r * 72 + k0];
            }
#pragma unroll
            for (int nf = 0; nf < 2; ++nf) {
                const int n = wc * 32 + nf * 16 + l15;
                bh[nf] = *(const bf16x8*)&ws_h[n * 72 + k0];
                bl[nf] = *(const bf16x8*)&ws_l[n * 72 + k0];
            }
#pragma unroll
            for (int mf = 0; mf < 4; ++mf)
#pragma unroll
                for (int nf = 0; nf < 2; ++nf) {
                    acc[mf][nf] = __builtin_amdgcn_mfma_f32_16x16x32_bf16(
                        ah[mf], bh[nf], acc[mf][nf], 0, 0, 0);
                    acc[mf][nf] = __builtin_amdgcn_mfma_f32_16x16x32_bf16(
                        al[mf], bh[nf], acc[mf][nf], 0, 0, 0);
                    acc[mf][nf] = __builtin_amdgcn_mfma_f32_16x16x32_bf16(
                        ah[mf], bl[nf], acc[mf][nf], 0, 0, 0);
                }
        }
    }
    __syncthreads();

    // ---- bias + leaky, split-write mid[m][k] (k = layer1 col) ----
#pragma unroll
    for (int nf = 0; nf < 2; ++nf) {
        const int col = wc * 32 + nf * 16 + l15;
        const float bias = b1[col];
#pragma unroll
        for (int mf = 0; mf < 4; ++mf)
#pragma unroll
            for (int j = 0; j < 4; ++j) {
                const int r = wr * 64 + mf * 16 + lg * 4 + j;
                float v = acc[mf][nf][j] + bias;
                v = v > 0.f ? v : NEG * v;
                ushort hi, lo;
                split1(v, hi, lo);
                mid_h[r * 136 + col] = hi;
                mid_l[r * 136 + col] = lo;
            }
    }
    __syncthreads();

    // ---- layer 2: K = 128, W2 fragments straight from global (L1-resident) ----
    f32x4 acc2[4];
#pragma unroll
    for (int i = 0; i < 4; ++i) acc2[i] = (f32x4)0.f;

#pragma unroll
    for (int ks2 = 0; ks2 < 4; ++ks2) {
        const int k0 = ks2 * 32 + lg * 8;
        bf16x8 ah[4], al[4];
#pragma unroll
        for (int mf = 0; mf < 4; ++mf) {
            const int r = wr * 64 + mf * 16 + l15;
            ah[mf] = *(const bf16x8*)&mid_h[r * 136 + k0];
            al[mf] = *(const bf16x8*)&mid_l[r * 136 + k0];
        }
        const int n = wc * 16 + l15;
        const bf16x8 bh = *(const bf16x8*)&W2t_h[n * 128 + k0];
        const bf16x8 bl = *(const bf16x8*)&W2t_l[n * 128 + k0];
#pragma unroll
        for (int mf = 0; mf < 4; ++mf) {
            acc2[mf] = __builtin_amdgcn_mfma_f32_16x16x32_bf16(
                ah[mf], bh, acc2[mf], 0, 0, 0);
            acc2[mf] = __builtin_amdgcn_mfma_f32_16x16x32_bf16(
                al[mf], bh, acc2[mf], 0, 0, 0);
            acc2[mf] = __builtin_amdgcn_mfma_f32_16x16x32_bf16(
                ah[mf], bl, acc2[mf], 0, 0, 0);
        }
    }

    // ---- store h as fp16 ----
    {
        const int col = wc * 16 + l15;
        const float b2c = b2[col];
#pragma unroll
        for (int mf = 0; mf < 4; ++mf)
#pragma unroll
            for (int j = 0; j < 4; ++j) {
                const int r = wr * 64 + mf * 16 + lg * 4 + j;
                if (r < rem)
                    h[(size_t)(v0 + r) * C_OUT + col] =
                        __float2half_rn(acc2[mf][j] + b2c);
            }
    }
}

// ---------------------------------------------------------------------------
// Phase A: radix partition into fixed-capacity bucket regions.
// Records packed to u32: (dst-in-bucket << 17) | payload.
// LDS-staged: rank per bucket in LDS, reorder, then stream out coalesced.
// ---------------------------------------------------------------------------
__global__ __launch_bounds__(256) void
partitionA_kernel(const int* __restrict__ hg_v, const int* __restrict__ hg_e,
                  const int* __restrict__ g_src, const int* __restrict__ g_dst,
                  int* __restrict__ bcur_e, int* __restrict__ bcur_vhg,
                  int* __restrict__ bcur_vg,
                  unsigned* __restrict__ rec_e, unsigned* __restrict__ rec_vhg,
                  unsigned* __restrict__ rec_vg) {
    __shared__ int hist[NB_MAX];
    __shared__ int lstart[NB_MAX];
    __shared__ int gb[NB_MAX];
    __shared__ int sscan[256];
    __shared__ unsigned lbuf[PAIRS_PER_BLOCK];        // 16 KB
    __shared__ unsigned char bkt8[PAIRS_PER_BLOCK];   // 4 KB
    const int t    = threadIdx.x;
    const int i0   = blockIdx.x * PAIRS_PER_BLOCK;
    const int vcnt = min(PAIRS_PER_BLOCK, N_INC - i0);

    for (int table = 0; table < 3; ++table) {
        const int *dsts, *pays; int *bcur; unsigned* rec; int shift, nb, cap;
        if (table == 0)      { dsts = hg_e;  pays = hg_v;  bcur = bcur_e;
                               rec = rec_e;   shift = EBSHIFT; nb = NB_E; cap = ECAP; }
        else if (table == 1) { dsts = hg_v;  pays = hg_e;  bcur = bcur_vhg;
                               rec = rec_vhg; shift = VBSHIFT; nb = NB_V; cap = VCAP; }
        else                 { dsts = g_dst; pays = g_src; bcur = bcur_vg;
                               rec = rec_vg;  shift = VBSHIFT; nb = NB_V; cap = VCAP; }
        const int dmask = (1 << shift) - 1;

        if (t < nb) hist[t] = 0;
        __syncthreads();

        unsigned pk[QP]; int bk[QP], rk[QP];
#pragma unroll
        for (int q = 0; q < QP; ++q) {
            const int i = i0 + t + q * 256;
            if (i < N_INC) {
                const int d = dsts[i];
                const int p = pays[i];
                bk[q] = d >> shift;
                pk[q] = ((unsigned)(d & dmask) << 17) | (unsigned)p;
                rk[q] = atomicAdd(&hist[bk[q]], 1);
            } else bk[q] = -1;
        }
        __syncthreads();

        // exclusive scan of hist -> lstart; reserve global runs via bcur
        {
            const int own = (t < nb) ? hist[t] : 0;
            sscan[t] = own;
            __syncthreads();
            for (int d2 = 1; d2 < 256; d2 <<= 1) {
                int v = (t >= d2) ? sscan[t - d2] : 0;
                __syncthreads();
                sscan[t] += v;
                __syncthreads();
            }
            if (t < nb) {
                lstart[t] = sscan[t] - own;
                gb[t] = own ? atomicAdd(&bcur[t], own) : 0;
            }
        }
        __syncthreads();

        // reorder into LDS, bucket-sorted
#pragma unroll
        for (int q = 0; q < QP; ++q) {
            if (bk[q] >= 0) {
                const int lp = lstart[bk[q]] + rk[q];
                lbuf[lp] = pk[q];
                bkt8[lp] = (unsigned char)bk[q];
            }
        }
        __syncthreads();

        // stream out: bucket-run coalescing
        for (int i = t; i < vcnt; i += 256) {
            const int b  = bkt8[i];
            const int pos = gb[b] + (i - lstart[b]);
            if (pos < cap)                         // statistically always true
                rec[(size_t)b * cap + pos] = lbuf[i];
        }
        __syncthreads();   // LDS reused next table
    }
}

// ---------------------------------------------------------------------------
// Phase B: per-bucket CSR derivation + dense slot build in LDS.
// Overwrites the record region IN-PLACE as the final slot array.
// ---------------------------------------------------------------------------
#define GRID_B (NB_E + 2 * NB_V)
__global__ __launch_bounds__(256) void
partitionB_kernel(unsigned* __restrict__ rec_e, unsigned* __restrict__ rec_vhg,
                  unsigned* __restrict__ rec_vg,
                  const int* __restrict__ bcur_e, const int* __restrict__ bcur_vhg,
                  const int* __restrict__ bcur_vg,
                  int* __restrict__ deg_e, int* __restrict__ deg_vhg,
                  int* __restrict__ deg_vg,
                  int* __restrict__ off_e, int* __restrict__ off_vhg,
                  int* __restrict__ off_vg) {
    __shared__ int slotbuf[ECAP];         // 48 KB (ECAP >= VCAP)
    __shared__ int cnt_l[1 << VBSHIFT];   // 2 KB
    __shared__ int cur_l[1 << VBSHIFT];   // 2 KB
    __shared__ int part[256];             // 1 KB

    int blk = blockIdx.x;
    unsigned* rec; const int* bcur; int* deg; int* off;
    int b, shift, ndst, cap;
    if (blk < NB_E) {
        rec = rec_e; bcur = bcur_e; deg = deg_e; off = off_e;
        shift = EBSHIFT; ndst = N_HGE; cap = ECAP; b = blk;
    } else if (blk < NB_E + NB_V) {
        rec = rec_vhg; bcur = bcur_vhg; deg = deg_vhg; off = off_vhg;
        shift = VBSHIFT; ndst = N_VERTS; cap = VCAP; b = blk - NB_E;
    } else {
        rec = rec_vg; bcur = bcur_vg; deg = deg_vg; off = off_vg;
        shift = VBSHIFT; ndst = N_VERTS; cap = VCAP; b = blk - NB_E - NB_V;
    }
    const int t    = threadIdx.x;
    const int dlo  = b << shift;
    const int nd   = 1 << shift;
    const int ndc  = min(nd, ndst - dlo);
    const int bs   = b * cap;
    const int bcnt = min(bcur[b], cap);

    // pass 1: per-dst counts in LDS
    for (int j = t; j < nd; j += 256) cnt_l[j] = 0;
    __syncthreads();
    for (int i = t; i < bcnt; i += 256)
        atomicAdd(&cnt_l[rec[bs + i] >> 17], 1);
    __syncthreads();

    // exclusive scan over nd (64 or 512) counts with 256 threads
    const int chunk = (nd + 255) / 256;     // 1 or 2
    const int lo = t * chunk;
    const int hi = min(lo + chunk, nd);
    int s = 0;
    for (int j = lo; j < hi; ++j) s += cnt_l[j];
    part[t] = s;
    __syncthreads();
    for (int d = 1; d < 256; d <<= 1) {
        int v = (t >= d) ? part[t - d] : 0;
        __syncthreads();
        part[t] += v;
        __syncthreads();
    }
    int run = (t > 0) ? part[t - 1] : 0;
    for (int j = lo; j < hi; ++j) { cur_l[j] = run; run += cnt_l[j]; }
    __syncthreads();

    // emit CSR (deg + global off into the padded slot layout), coalesced
    for (int j = t; j < ndc; j += 256) {
        deg[dlo + j] = cnt_l[j];
        off[dlo + j] = bs + cur_l[j];
    }
    __syncthreads();   // cur_l becomes the scatter cursor below

    // pass 2: scatter payloads into LDS, then overwrite rec in-place as slots
    for (int i = t; i < bcnt; i += 256) {
        const unsigned r = rec[bs + i];
        const int lpos = atomicAdd(&cur_l[r >> 17], 1);
        slotbuf[lpos] = (int)(r & 0x1FFFFu);
    }
    __syncthreads();
    for (int i = t; i < bcnt; i += 256)
        rec[bs + i] = (unsigned)slotbuf[i];
}

// ---------------------------------------------------------------------------
// v2e gather: one wave per hyperedge, 8 slots/instr (8 lanes/row, 16B uint4
// loads). sub = lane>>3 picks slot, cp = lane&7 picks channel octet.
// ---------------------------------------------------------------------------
__global__ void gather_e_kernel(const int* __restrict__ slot, const int* __restrict__ off,
                                const int* __restrict__ deg, const __half* __restrict__ h,
                                __half* __restrict__ e_feat) {
    const int wid  = (blockIdx.x * blockDim.x + threadIdx.x) >> 6;
    const int lane = threadIdx.x & 63;
    if (wid >= N_HGE) return;
    const int sub = lane >> 3;
    const int cp  = lane & 7;
    const int n    = deg[wid];
    const int base = off[wid];

    float4 a0 = make_float4(0.f, 0.f, 0.f, 0.f);
    float4 a1 = make_float4(0.f, 0.f, 0.f, 0.f);
    int j = 0;
    for (; j + 16 <= n; j += 16) {
        const int s0 = slot[base + j + sub];
        const int s1 = slot[base + j + 8 + sub];
        const uint4 p0 = *(const uint4*)&h[(unsigned)(s0 * C_OUT + 8 * cp)];
        const uint4 p1 = *(const uint4*)&h[(unsigned)(s1 * C_OUT + 8 * cp)];
        h8acc(a0, a1, p0);
        h8acc(a0, a1, p1);
    }
    for (; j < n; j += 8) {                      // guarded octet tail
        const int idx = j + sub;
        const int s = slot[base + (idx < n ? idx : 0)];
        const uint4 p = *(const uint4*)&h[(unsigned)(s * C_OUT + 8 * cp)];
        if (idx < n) h8acc(a0, a1, p);
    }
    xreduce8(a0, a1);
    const float inv = 1.f / fmaxf((float)n, 1.f);
    if (sub == 0) {
        const __half2 r0 = __float22half2_rn(make_float2(a0.x * inv, a0.y * inv));
        const __half2 r1 = __float22half2_rn(make_float2(a0.z * inv, a0.w * inv));
        const __half2 r2 = __float22half2_rn(make_float2(a1.x * inv, a1.y * inv));
        const __half2 r3 = __float22half2_rn(make_float2(a1.z * inv, a1.w * inv));
        uint4 pk;
        pk.x = *(const unsigned*)&r0;
        pk.y = *(const unsigned*)&r1;
        pk.z = *(const unsigned*)&r2;
        pk.w = *(const unsigned*)&r3;
        *(uint4*)&e_feat[(unsigned)(wid * C_OUT + 8 * cp)] = pk;
    }
}

// ---------------------------------------------------------------------------
// Fused per-vertex epilogue, 8-slot/16B gathers over e_feat and h.
// ---------------------------------------------------------------------------
__global__ void vertex_out_kernel(const int* __restrict__ slot_vhg,
                                  const int* __restrict__ off_vhg,
                                  const int* __restrict__ deg_vhg,
                                  const int* __restrict__ slot_vg,
                                  const int* __restrict__ off_vg,
                                  const int* __restrict__ deg_vg,
                                  const __half* __restrict__ e_feat,
                                  const __half* __restrict__ h,
                                  const float* __restrict__ w,
                                  float* __restrict__ out) {
    const int wid  = (blockIdx.x * blockDim.x + threadIdx.x) >> 6;
    const int lane = threadIdx.x & 63;
    if (wid >= N_VERTS) return;
    const int sub = lane >> 3;
    const int cp  = lane & 7;

    float4 hg0 = make_float4(0.f, 0.f, 0.f, 0.f);
    float4 hg1 = make_float4(0.f, 0.f, 0.f, 0.f);
    float inv_hg;
    {
        const int n = deg_vhg[wid];
        const int base = off_vhg[wid];
        int j = 0;
        for (; j + 16 <= n; j += 16) {
            const int s0 = slot_vhg[base + j + sub];
            const int s1 = slot_vhg[base + j + 8 + sub];
            const uint4 p0 = *(const uint4*)&e_feat[(unsigned)(s0 * C_OUT + 8 * cp)];
            const uint4 p1 = *(const uint4*)&e_feat[(unsigned)(s1 * C_OUT + 8 * cp)];
            h8acc(hg0, hg1, p0);
            h8acc(hg0, hg1, p1);
        }
        for (; j < n; j += 8) {
            const int idx = j + sub;
            const int s = slot_vhg[base + (idx < n ? idx : 0)];
            const uint4 p = *(const uint4*)&e_feat[(unsigned)(s * C_OUT + 8 * cp)];
            if (idx < n) h8acc(hg0, hg1, p);
        }
        inv_hg = 1.f / fmaxf((float)n, 1.f);
    }

    float4 g0 = make_float4(0.f, 0.f, 0.f, 0.f);
    float4 g1 = make_float4(0.f, 0.f, 0.f, 0.f);
    float inv_g;
    {
        const int n = deg_vg[wid];
        const int base = off_vg[wid];
        int j = 0;
        for (; j + 16 <= n; j += 16) {
            const int s0 = slot_vg[base + j + sub];
            const int s1 = slot_vg[base + j + 8 + sub];
            const uint4 p0 = *(const uint4*)&h[(unsigned)(s0 * C_OUT + 8 * cp)];
            const uint4 p1 = *(const uint4*)&h[(unsigned)(s1 * C_OUT + 8 * cp)];
            h8acc(g0, g1, p0);
            h8acc(g0, g1, p1);
        }
        for (; j < n; j += 8) {
            const int idx = j + sub;
            const int s = slot_vg[base + (idx < n ? idx : 0)];
            const uint4 p = *(const uint4*)&h[(unsigned)(s * C_OUT + 8 * cp)];
            if (idx < n) h8acc(g0, g1, p);
        }
        inv_g = 1.f / fmaxf((float)n, 1.f);
    }

    xreduce8(hg0, hg1);
    xreduce8(g0, g1);

    const float w0 = w[0], w1 = w[1];
    const float m  = fmaxf(w0, w1);
    const float e0 = __expf(w0 - m), e1 = __expf(w1 - m);
    const float sw0 = e0 / (e0 + e1), sw1 = e1 / (e0 + e1);
    const float c0 = sw0 * 0.5f;

    float4 hv0 = make_float4(0.f, 0.f, 0.f, 0.f);
    float4 hv1 = make_float4(0.f, 0.f, 0.f, 0.f);
    h8acc(hv0, hv1, *(const uint4*)&h[(unsigned)(wid * C_OUT + 8 * cp)]);

    float4 o0, o1;
    o0.x = c0 * (g0.x * inv_g + hg0.x * inv_hg) + sw1 * hv0.x;
    o0.y = c0 * (g0.y * inv_g + hg0.y * inv_hg) + sw1 * hv0.y;
    o0.z = c0 * (g0.z * inv_g + hg0.z * inv_hg) + sw1 * hv0.z;
    o0.w = c0 * (g0.w * inv_g + hg0.w * inv_hg) + sw1 * hv0.w;
    o1.x = c0 * (g1.x * inv_g + hg1.x * inv_hg) + sw1 * hv1.x;
    o1.y = c0 * (g1.y * inv_g + hg1.y * inv_hg) + sw1 * hv1.y;
    o1.z = c0 * (g1.z * inv_g + hg1.z * inv_hg) + sw1 * hv1.z;
    o1.w = c0 * (g1.w * inv_g + hg1.w * inv_hg) + sw1 * hv1.w;
    o0.x = o0.x > 0.f ? o0.x : NEG * o0.x;
    o0.y = o0.y > 0.f ? o0.y : NEG * o0.y;
    o0.z = o0.z > 0.f ? o0.z : NEG * o0.z;
    o0.w = o0.w > 0.f ? o0.w : NEG * o0.w;
    o1.x = o1.x > 0.f ? o1.x : NEG * o1.x;
    o1.y = o1.y > 0.f ? o1.y : NEG * o1.y;
    o1.z = o1.z > 0.f ? o1.z : NEG * o1.z;
    o1.w = o1.w > 0.f ? o1.w : NEG * o1.w;

    if (sub == 0) {
        *(float4*)&out[(unsigned)(wid * C_OUT + 8 * cp)]     = o0;
        *(float4*)&out[(unsigned)(wid * C_OUT + 8 * cp + 4)] = o1;
    }
}

// ---------------------------------------------------------------------------
extern "C" void kernel_launch(void* const* d_in, const int* in_sizes, int n_in,
                              void* d_out, int out_size, void* d_ws, size_t ws_size,
                              hipStream_t stream) {
    const float* x    = (const float*)d_in[0];
    const float* W1   = (const float*)d_in[1];
    const float* b1   = (const float*)d_in[2];
    const float* W2   = (const float*)d_in[3];
    const float* b2   = (const float*)d_in[4];
    const float* w    = (const float*)d_in[5];
    const int*  hg_v  = (const int*)d_in[6];
    const int*  hg_e  = (const int*)d_in[7];
    const int*  g_src = (const int*)d_in[8];
    const int*  g_dst = (const int*)d_in[9];
    float* out = (float*)d_out;

    // ---- workspace layout (~40 MB total) ----
    unsigned* rec_e   = (unsigned*)d_ws;                       // 157*12288 u32
    unsigned* rec_vhg = rec_e   + (size_t)NB_E * ECAP;         // 196*10240 u32
    unsigned* rec_vg  = rec_vhg + (size_t)NB_V * VCAP;         // 196*10240 u32
    // zeroed int region:
    int* bcur_e    = (int*)(rec_vg + (size_t)NB_V * VCAP);     // NB_E
    int* bcur_vhg  = bcur_e   + NB_E;                          // NB_V
    int* bcur_vg   = bcur_vhg + NB_V;                          // NB_V
    // not zeroed:
    int* deg_e     = bcur_vg  + NB_V;                          // N_HGE
    int* deg_vhg   = deg_e    + N_HGE;                         // N_VERTS
    int* deg_vg    = deg_vhg  + N_VERTS;                       // N_VERTS
    int* off_e     = deg_vg   + N_VERTS;                       // N_HGE
    int* off_vhg   = off_e    + N_HGE;                         // N_VERTS
    int* off_vg    = off_vhg  + N_VERTS;                       // N_VERTS
    // fp16 feature arrays — 256B-aligned (round-8 lesson: misaligned h made
    // every 128B gathered row straddle 3 cache lines; FETCH 120->211 MB)
    uintptr_t hp   = ((uintptr_t)(off_vg + N_VERTS) + 255) & ~(uintptr_t)255;
    __half* h      = (__half*)hp;                              // N_VERTS*64 fp16
    __half* e_feat = h + (size_t)N_VERTS * C_OUT;              // N_HGE*64 fp16
    ushort* W1t_h  = (ushort*)(e_feat + (size_t)N_HGE * C_OUT);
    ushort* W1t_l  = W1t_h + C_IN * C_MID;
    ushort* W2t_h  = W1t_l + C_IN * C_MID;
    ushort* W2t_l  = W2t_h + C_MID * C_OUT;

    hipMemsetAsync(bcur_e, 0, (NB_E + 2 * NB_V) * sizeof(int), stream);

    // ---- partition (no count prepass: fixed-capacity buckets) ----
    const int partA_blocks = (N_INC + PAIRS_PER_BLOCK - 1) / PAIRS_PER_BLOCK;
    partitionA_kernel<<<partA_blocks, 256, 0, stream>>>(
        hg_v, hg_e, g_src, g_dst, bcur_e, bcur_vhg, bcur_vg,
        rec_e, rec_vhg, rec_vg);
    partitionB_kernel<<<GRID_B, 256, 0, stream>>>(
        rec_e, rec_vhg, rec_vg, bcur_e, bcur_vhg, bcur_vg,
        deg_e, deg_vhg, deg_vg, off_e, off_vhg, off_vg);

    // ---- weight split ----
    prep_w_kernel<<<(C_IN * C_MID + C_MID * C_OUT + 255) / 256, 256, 0, stream>>>(
        W1, W2, W1t_h, W1t_l, W2t_h, W2t_l);

    // ---- MFMA MLP (512-thread blocks) ----
    mlp_mfma_kernel<<<(N_VERTS + MBM - 1) / MBM, 512, 0, stream>>>(
        x, W1t_h, W1t_l, W2t_h, W2t_l, b1, b2, h);

    // ---- v2e gather ----
    const int ge_blocks = (int)(((size_t)N_HGE * 64 + 255) / 256);
    gather_e_kernel<<<ge_blocks, 256, 0, stream>>>((const int*)rec_e, off_e, deg_e,
                                                   h, e_feat);

    // ---- fused e2v + graph gather + finalize ----
    const int vo_blocks = (int)(((size_t)N_VERTS * 64 + 255) / 256);
    vertex_out_kernel<<<vo_blocks, 256, 0, stream>>>(
        (const int*)rec_vhg, off_vhg, deg_vhg,
        (const int*)rec_vg,  off_vg,  deg_vg,
        e_feat, h, w, out);
}

// Round 10
// 390.854 us; speedup vs baseline: 1.5120x; 1.0370x over previous
//
#include <hip/hip_runtime.h>
#include <hip/hip_bf16.h>
#include <hip/hip_fp16.h>

// Problem constants (fixed by the reference setup)
#define N_VERTS   100000
#define N_HGE     10000
#define N_INC     1600000
#define N_EDGES   1600000
#define C_IN      256
#define C_MID     128
#define C_OUT     64
#define NEG       0.2f

// Radix-partition parameters. Fixed-capacity bucket regions:
//   E-buckets: 64 hyperedges, mean 10240 records, cap 12288
//   V-buckets: 512 vertices,  mean  8192 records, cap 10240
// Caps are statistically unreachable for this fixed input; writes are
// bounds-guarded so even an overflow cannot corrupt memory.
#define EBSHIFT 6
#define NB_E    157              // ceil(10000/64)
#define VBSHIFT 9
#define NB_V    196              // ceil(100000/512)
#define NB_MAX  196
#define ECAP    12288
#define VCAP    10240
#define PAIRS_PER_BLOCK 4096     // 256 threads x 16
#define QP 16

typedef __attribute__((ext_vector_type(8))) _Float16 f16x8;
typedef __attribute__((ext_vector_type(4))) float    f32x4;

// Pack two floats into fp16x2 bits.
__device__ __forceinline__ unsigned packh2(float a, float b) {
    const __half2 h = __float22half2_rn(make_float2(a, b));
    return *(const unsigned*)&h;
}
__device__ __forceinline__ ushort h1bits(float v) {
    const __half x = __float2half_rn(v);
    return *(const ushort*)&x;
}

// Unpack 8 fp16 (as uint4) and accumulate into two float4s.
__device__ __forceinline__ void h8acc(float4& a0, float4& a1, uint4 p) {
    const float2 f0 = __half22float2(*(__half2*)&p.x);
    const float2 f1 = __half22float2(*(__half2*)&p.y);
    const float2 f2 = __half22float2(*(__half2*)&p.z);
    const float2 f3 = __half22float2(*(__half2*)&p.w);
    a0.x += f0.x; a0.y += f0.y; a0.z += f1.x; a0.w += f1.y;
    a1.x += f2.x; a1.y += f2.y; a1.z += f3.x; a1.w += f3.y;
}

// Sum 8 floats across the 8 sub-groups (lanes l, l^8, l^16, ..., l^56).
__device__ __forceinline__ void xreduce8(float4& a, float4& b) {
#pragma unroll
    for (int m = 8; m <= 32; m <<= 1) {
        a.x += __shfl_xor(a.x, m); a.y += __shfl_xor(a.y, m);
        a.z += __shfl_xor(a.z, m); a.w += __shfl_xor(a.w, m);
        b.x += __shfl_xor(b.x, m); b.y += __shfl_xor(b.y, m);
        b.z += __shfl_xor(b.z, m); b.w += __shfl_xor(b.w, m);
    }
}

// ---------------------------------------------------------------------------
// One-time weight prep: W1/W2 -> fp16, TRANSPOSED to [n][k].
// ---------------------------------------------------------------------------
__global__ __launch_bounds__(256) void
prep_w_kernel(const float* __restrict__ W1, const float* __restrict__ W2,
              ushort* __restrict__ W1t, ushort* __restrict__ W2t) {
    const int idx = blockIdx.x * 256 + threadIdx.x;
    if (idx < C_IN * C_MID) {                       // W1t[n][k], n<128,k<256
        const int n = idx >> 8, k = idx & 255;
        W1t[idx] = h1bits(W1[k * C_MID + n]);
    } else {
        const int j = idx - C_IN * C_MID;
        if (j < C_MID * C_OUT) {                    // W2t[n][k], n<64,k<128
            const int n = j >> 7, k = j & 127;
            W2t[j] = h1bits(W2[k * C_OUT + n]);
        }
    }
}

// ---------------------------------------------------------------------------
// MFMA MLP, fp16: h = leaky_relu(x @ W1 + b1) @ W2 + b2.
// fp16 inputs (2^-11 rel quantization — comparable to the fp16 h-storage
// rounding already in the pipeline) with fp32 MFMA accumulation.
// vs round-9 split-bf16: MFMA count /3, LDS /2 (36 KB -> 4 blocks/CU,
// 32 waves/CU), staging VALU /3. 512 threads, 8 waves in 2x4 over 128 rows.
// Fragment maps [m89] (dtype-independent): A: row=l&15, k=(l>>4)*8+e;
// B: col=l&15, same k; C/D: col=l&15, row=(l>>4)*4+reg.
// ---------------------------------------------------------------------------
#define MBM 128
__global__ __launch_bounds__(512) void
mlp_mfma_kernel(const float* __restrict__ x,
                const ushort* __restrict__ W1t, const ushort* __restrict__ W2t,
                const float* __restrict__ b1, const float* __restrict__ b2,
                __half* __restrict__ h) {
    // union LDS: phase1 = xs/ws [128][72]; phase2 = mid [128][136]  (36 KB)
    __shared__ ushort buf[18432];
    ushort* xs  = buf;            // [128][72]
    ushort* ws  = buf + 9216;     // [128][72]
    ushort* mid = buf;            // [128][136]

    const int t    = threadIdx.x;
    const int lane = t & 63;
    const int wid  = t >> 6;                       // 0..7
    const int wr   = wid >> 2, wc = wid & 3;       // 2x4 wave grid
    const int v0   = blockIdx.x * MBM;
    const int rem  = N_VERTS - v0;                 // <128 only in last block
    const int l15  = lane & 15;
    const int lg   = lane >> 4;                    // 0..3

    f32x4 acc[4][2];
#pragma unroll
    for (int i = 0; i < 4; ++i) { acc[i][0] = (f32x4)0.f; acc[i][1] = (f32x4)0.f; }

    // ---- layer 1: K tiled by 64 (4 tiles), fp16 staged in LDS ----
    for (int kt = 0; kt < 4; ++kt) {
        __syncthreads();
#pragma unroll
        for (int it = 0; it < 4; ++it) {           // x tile: 2048 float4
            const int idx = it * 512 + t;
            const int row = idx >> 4;
            const int c4  = (idx & 15) * 4;
            float4 v = make_float4(0.f, 0.f, 0.f, 0.f);
            if (row < rem)
                v = *(const float4*)&x[(size_t)(v0 + row) * C_IN + kt * 64 + c4];
            uint2 p;
            p.x = packh2(v.x, v.y);
            p.y = packh2(v.z, v.w);
            *(uint2*)&xs[row * 72 + c4] = p;
        }
#pragma unroll
        for (int it = 0; it < 4; ++it) {           // W1t tile (fp16 in global)
            const int idx = it * 512 + t;
            const int n  = idx >> 4;
            const int c4 = (idx & 15) * 4;
            *(uint2*)&ws[n * 72 + c4] = *(const uint2*)&W1t[n * 256 + kt * 64 + c4];
        }
        __syncthreads();

#pragma unroll
        for (int ks = 0; ks < 2; ++ks) {
            const int k0 = ks * 32 + lg * 8;
            f16x8 a[4], b[2];
#pragma unroll
            for (int mf = 0; mf < 4; ++mf)
                a[mf] = *(const f16x8*)&xs[(wr * 64 + mf * 16 + l15) * 72 + k0];
#pragma unroll
            for (int nf = 0; nf < 2; ++nf)
                b[nf] = *(const f16x8*)&ws[(wc * 32 + nf * 16 + l15) * 72 + k0];
#pragma unroll
            for (int mf = 0; mf < 4; ++mf)
#pragma unroll
                for (int nf = 0; nf < 2; ++nf)
                    acc[mf][nf] = __builtin_amdgcn_mfma_f32_16x16x32_f16(
                        a[mf], b[nf], acc[mf][nf], 0, 0, 0);
        }
    }
    __syncthreads();

    // ---- bias + leaky, fp16 write mid[m][k] (k = layer1 col) ----
#pragma unroll
    for (int nf = 0; nf < 2; ++nf) {
        const int col = wc * 32 + nf * 16 + l15;
        const float bias = b1[col];
#pragma unroll
        for (int mf = 0; mf < 4; ++mf)
#pragma unroll
            for (int j = 0; j < 4; ++j) {
                const int r = wr * 64 + mf * 16 + lg * 4 + j;
                float v = acc[mf][nf][j] + bias;
                v = v > 0.f ? v : NEG * v;
                mid[r * 136 + col] = h1bits(v);
            }
    }
    __syncthreads();

    // ---- layer 2: K = 128, W2 fragments straight from global (L1-resident) ----
    f32x4 acc2[4];
#pragma unroll
    for (int i = 0; i < 4; ++i) acc2[i] = (f32x4)0.f;

#pragma unroll
    for (int ks2 = 0; ks2 < 4; ++ks2) {
        const int k0 = ks2 * 32 + lg * 8;
        f16x8 a[4];
#pragma unroll
        for (int mf = 0; mf < 4; ++mf)
            a[mf] = *(const f16x8*)&mid[(wr * 64 + mf * 16 + l15) * 136 + k0];
        const f16x8 b = *(const f16x8*)&W2t[(wc * 16 + l15) * 128 + k0];
#pragma unroll
        for (int mf = 0; mf < 4; ++mf)
            acc2[mf] = __builtin_amdgcn_mfma_f32_16x16x32_f16(
                a[mf], b, acc2[mf], 0, 0, 0);
    }

    // ---- store h as fp16 ----
    {
        const int col = wc * 16 + l15;
        const float b2c = b2[col];
#pragma unroll
        for (int mf = 0; mf < 4; ++mf)
#pragma unroll
            for (int j = 0; j < 4; ++j) {
                const int r = wr * 64 + mf * 16 + lg * 4 + j;
                if (r < rem)
                    h[(size_t)(v0 + r) * C_OUT + col] =
                        __float2half_rn(acc2[mf][j] + b2c);
            }
    }
}

// ---------------------------------------------------------------------------
// Phase A: radix partition into fixed-capacity bucket regions.
// Records packed to u32: (dst-in-bucket << 17) | payload.
// LDS-staged: rank per bucket in LDS, reorder, then stream out coalesced.
// ---------------------------------------------------------------------------
__global__ __launch_bounds__(256) void
partitionA_kernel(const int* __restrict__ hg_v, const int* __restrict__ hg_e,
                  const int* __restrict__ g_src, const int* __restrict__ g_dst,
                  int* __restrict__ bcur_e, int* __restrict__ bcur_vhg,
                  int* __restrict__ bcur_vg,
                  unsigned* __restrict__ rec_e, unsigned* __restrict__ rec_vhg,
                  unsigned* __restrict__ rec_vg) {
    __shared__ int hist[NB_MAX];
    __shared__ int lstart[NB_MAX];
    __shared__ int gb[NB_MAX];
    __shared__ int sscan[256];
    __shared__ unsigned lbuf[PAIRS_PER_BLOCK];        // 16 KB
    __shared__ unsigned char bkt8[PAIRS_PER_BLOCK];   // 4 KB
    const int t    = threadIdx.x;
    const int i0   = blockIdx.x * PAIRS_PER_BLOCK;
    const int vcnt = min(PAIRS_PER_BLOCK, N_INC - i0);

    for (int table = 0; table < 3; ++table) {
        const int *dsts, *pays; int *bcur; unsigned* rec; int shift, nb, cap;
        if (table == 0)      { dsts = hg_e;  pays = hg_v;  bcur = bcur_e;
                               rec = rec_e;   shift = EBSHIFT; nb = NB_E; cap = ECAP; }
        else if (table == 1) { dsts = hg_v;  pays = hg_e;  bcur = bcur_vhg;
                               rec = rec_vhg; shift = VBSHIFT; nb = NB_V; cap = VCAP; }
        else                 { dsts = g_dst; pays = g_src; bcur = bcur_vg;
                               rec = rec_vg;  shift = VBSHIFT; nb = NB_V; cap = VCAP; }
        const int dmask = (1 << shift) - 1;

        if (t < nb) hist[t] = 0;
        __syncthreads();

        unsigned pk[QP]; int bk[QP], rk[QP];
#pragma unroll
        for (int q = 0; q < QP; ++q) {
            const int i = i0 + t + q * 256;
            if (i < N_INC) {
                const int d = dsts[i];
                const int p = pays[i];
                bk[q] = d >> shift;
                pk[q] = ((unsigned)(d & dmask) << 17) | (unsigned)p;
                rk[q] = atomicAdd(&hist[bk[q]], 1);
            } else bk[q] = -1;
        }
        __syncthreads();

        // exclusive scan of hist -> lstart; reserve global runs via bcur
        {
            const int own = (t < nb) ? hist[t] : 0;
            sscan[t] = own;
            __syncthreads();
            for (int d2 = 1; d2 < 256; d2 <<= 1) {
                int v = (t >= d2) ? sscan[t - d2] : 0;
                __syncthreads();
                sscan[t] += v;
                __syncthreads();
            }
            if (t < nb) {
                lstart[t] = sscan[t] - own;
                gb[t] = own ? atomicAdd(&bcur[t], own) : 0;
            }
        }
        __syncthreads();

        // reorder into LDS, bucket-sorted
#pragma unroll
        for (int q = 0; q < QP; ++q) {
            if (bk[q] >= 0) {
                const int lp = lstart[bk[q]] + rk[q];
                lbuf[lp] = pk[q];
                bkt8[lp] = (unsigned char)bk[q];
            }
        }
        __syncthreads();

        // stream out: bucket-run coalescing
        for (int i = t; i < vcnt; i += 256) {
            const int b  = bkt8[i];
            const int pos = gb[b] + (i - lstart[b]);
            if (pos < cap)                         // statistically always true
                rec[(size_t)b * cap + pos] = lbuf[i];
        }
        __syncthreads();   // LDS reused next table
    }
}

// ---------------------------------------------------------------------------
// Phase B: per-bucket CSR derivation + dense slot build in LDS.
// Overwrites the record region IN-PLACE as the final slot array.
// ---------------------------------------------------------------------------
#define GRID_B (NB_E + 2 * NB_V)
__global__ __launch_bounds__(256) void
partitionB_kernel(unsigned* __restrict__ rec_e, unsigned* __restrict__ rec_vhg,
                  unsigned* __restrict__ rec_vg,
                  const int* __restrict__ bcur_e, const int* __restrict__ bcur_vhg,
                  const int* __restrict__ bcur_vg,
                  int* __restrict__ deg_e, int* __restrict__ deg_vhg,
                  int* __restrict__ deg_vg,
                  int* __restrict__ off_e, int* __restrict__ off_vhg,
                  int* __restrict__ off_vg) {
    __shared__ int slotbuf[ECAP];         // 48 KB (ECAP >= VCAP)
    __shared__ int cnt_l[1 << VBSHIFT];   // 2 KB
    __shared__ int cur_l[1 << VBSHIFT];   // 2 KB
    __shared__ int part[256];             // 1 KB

    int blk = blockIdx.x;
    unsigned* rec; const int* bcur; int* deg; int* off;
    int b, shift, ndst, cap;
    if (blk < NB_E) {
        rec = rec_e; bcur = bcur_e; deg = deg_e; off = off_e;
        shift = EBSHIFT; ndst = N_HGE; cap = ECAP; b = blk;
    } else if (blk < NB_E + NB_V) {
        rec = rec_vhg; bcur = bcur_vhg; deg = deg_vhg; off = off_vhg;
        shift = VBSHIFT; ndst = N_VERTS; cap = VCAP; b = blk - NB_E;
    } else {
        rec = rec_vg; bcur = bcur_vg; deg = deg_vg; off = off_vg;
        shift = VBSHIFT; ndst = N_VERTS; cap = VCAP; b = blk - NB_E - NB_V;
    }
    const int t    = threadIdx.x;
    const int dlo  = b << shift;
    const int nd   = 1 << shift;
    const int ndc  = min(nd, ndst - dlo);
    const int bs   = b * cap;
    const int bcnt = min(bcur[b], cap);

    // pass 1: per-dst counts in LDS
    for (int j = t; j < nd; j += 256) cnt_l[j] = 0;
    __syncthreads();
    for (int i = t; i < bcnt; i += 256)
        atomicAdd(&cnt_l[rec[bs + i] >> 17], 1);
    __syncthreads();

    // exclusive scan over nd (64 or 512) counts with 256 threads
    const int chunk = (nd + 255) / 256;     // 1 or 2
    const int lo = t * chunk;
    const int hi = min(lo + chunk, nd);
    int s = 0;
    for (int j = lo; j < hi; ++j) s += cnt_l[j];
    part[t] = s;
    __syncthreads();
    for (int d = 1; d < 256; d <<= 1) {
        int v = (t >= d) ? part[t - d] : 0;
        __syncthreads();
        part[t] += v;
        __syncthreads();
    }
    int run = (t > 0) ? part[t - 1] : 0;
    for (int j = lo; j < hi; ++j) { cur_l[j] = run; run += cnt_l[j]; }
    __syncthreads();

    // emit CSR (deg + global off into the padded slot layout), coalesced
    for (int j = t; j < ndc; j += 256) {
        deg[dlo + j] = cnt_l[j];
        off[dlo + j] = bs + cur_l[j];
    }
    __syncthreads();   // cur_l becomes the scatter cursor below

    // pass 2: scatter payloads into LDS, then overwrite rec in-place as slots
    for (int i = t; i < bcnt; i += 256) {
        const unsigned r = rec[bs + i];
        const int lpos = atomicAdd(&cur_l[r >> 17], 1);
        slotbuf[lpos] = (int)(r & 0x1FFFFu);
    }
    __syncthreads();
    for (int i = t; i < bcnt; i += 256)
        rec[bs + i] = (unsigned)slotbuf[i];
}

// ---------------------------------------------------------------------------
// v2e gather: one wave per hyperedge, 8 slots/instr (8 lanes/row, 16B uint4
// loads). sub = lane>>3 picks slot, cp = lane&7 picks channel octet.
// ---------------------------------------------------------------------------
__global__ void gather_e_kernel(const int* __restrict__ slot, const int* __restrict__ off,
                                const int* __restrict__ deg, const __half* __restrict__ h,
                                __half* __restrict__ e_feat) {
    const int wid  = (blockIdx.x * blockDim.x + threadIdx.x) >> 6;
    const int lane = threadIdx.x & 63;
    if (wid >= N_HGE) return;
    const int sub = lane >> 3;
    const int cp  = lane & 7;
    const int n    = deg[wid];
    const int base = off[wid];

    float4 a0 = make_float4(0.f, 0.f, 0.f, 0.f);
    float4 a1 = make_float4(0.f, 0.f, 0.f, 0.f);
    int j = 0;
    for (; j + 16 <= n; j += 16) {
        const int s0 = slot[base + j + sub];
        const int s1 = slot[base + j + 8 + sub];
        const uint4 p0 = *(const uint4*)&h[(unsigned)(s0 * C_OUT + 8 * cp)];
        const uint4 p1 = *(const uint4*)&h[(unsigned)(s1 * C_OUT + 8 * cp)];
        h8acc(a0, a1, p0);
        h8acc(a0, a1, p1);
    }
    for (; j < n; j += 8) {                      // guarded octet tail
        const int idx = j + sub;
        const int s = slot[base + (idx < n ? idx : 0)];
        const uint4 p = *(const uint4*)&h[(unsigned)(s * C_OUT + 8 * cp)];
        if (idx < n) h8acc(a0, a1, p);
    }
    xreduce8(a0, a1);
    const float inv = 1.f / fmaxf((float)n, 1.f);
    if (sub == 0) {
        const __half2 r0 = __float22half2_rn(make_float2(a0.x * inv, a0.y * inv));
        const __half2 r1 = __float22half2_rn(make_float2(a0.z * inv, a0.w * inv));
        const __half2 r2 = __float22half2_rn(make_float2(a1.x * inv, a1.y * inv));
        const __half2 r3 = __float22half2_rn(make_float2(a1.z * inv, a1.w * inv));
        uint4 pk;
        pk.x = *(const unsigned*)&r0;
        pk.y = *(const unsigned*)&r1;
        pk.z = *(const unsigned*)&r2;
        pk.w = *(const unsigned*)&r3;
        *(uint4*)&e_feat[(unsigned)(wid * C_OUT + 8 * cp)] = pk;
    }
}

// ---------------------------------------------------------------------------
// Fused per-vertex epilogue, 8-slot/16B gathers over e_feat and h.
// ---------------------------------------------------------------------------
__global__ void vertex_out_kernel(const int* __restrict__ slot_vhg,
                                  const int* __restrict__ off_vhg,
                                  const int* __restrict__ deg_vhg,
                                  const int* __restrict__ slot_vg,
                                  const int* __restrict__ off_vg,
                                  const int* __restrict__ deg_vg,
                                  const __half* __restrict__ e_feat,
                                  const __half* __restrict__ h,
                                  const float* __restrict__ w,
                                  float* __restrict__ out) {
    const int wid  = (blockIdx.x * blockDim.x + threadIdx.x) >> 6;
    const int lane = threadIdx.x & 63;
    if (wid >= N_VERTS) return;
    const int sub = lane >> 3;
    const int cp  = lane & 7;

    float4 hg0 = make_float4(0.f, 0.f, 0.f, 0.f);
    float4 hg1 = make_float4(0.f, 0.f, 0.f, 0.f);
    float inv_hg;
    {
        const int n = deg_vhg[wid];
        const int base = off_vhg[wid];
        int j = 0;
        for (; j + 16 <= n; j += 16) {
            const int s0 = slot_vhg[base + j + sub];
            const int s1 = slot_vhg[base + j + 8 + sub];
            const uint4 p0 = *(const uint4*)&e_feat[(unsigned)(s0 * C_OUT + 8 * cp)];
            const uint4 p1 = *(const uint4*)&e_feat[(unsigned)(s1 * C_OUT + 8 * cp)];
            h8acc(hg0, hg1, p0);
            h8acc(hg0, hg1, p1);
        }
        for (; j < n; j += 8) {
            const int idx = j + sub;
            const int s = slot_vhg[base + (idx < n ? idx : 0)];
            const uint4 p = *(const uint4*)&e_feat[(unsigned)(s * C_OUT + 8 * cp)];
            if (idx < n) h8acc(hg0, hg1, p);
        }
        inv_hg = 1.f / fmaxf((float)n, 1.f);
    }

    float4 g0 = make_float4(0.f, 0.f, 0.f, 0.f);
    float4 g1 = make_float4(0.f, 0.f, 0.f, 0.f);
    float inv_g;
    {
        const int n = deg_vg[wid];
        const int base = off_vg[wid];
        int j = 0;
        for (; j + 16 <= n; j += 16) {
            const int s0 = slot_vg[base + j + sub];
            const int s1 = slot_vg[base + j + 8 + sub];
            const uint4 p0 = *(const uint4*)&h[(unsigned)(s0 * C_OUT + 8 * cp)];
            const uint4 p1 = *(const uint4*)&h[(unsigned)(s1 * C_OUT + 8 * cp)];
            h8acc(g0, g1, p0);
            h8acc(g0, g1, p1);
        }
        for (; j < n; j += 8) {
            const int idx = j + sub;
            const int s = slot_vg[base + (idx < n ? idx : 0)];
            const uint4 p = *(const uint4*)&h[(unsigned)(s * C_OUT + 8 * cp)];
            if (idx < n) h8acc(g0, g1, p);
        }
        inv_g = 1.f / fmaxf((float)n, 1.f);
    }

    xreduce8(hg0, hg1);
    xreduce8(g0, g1);

    const float w0 = w[0], w1 = w[1];
    const float m  = fmaxf(w0, w1);
    const float e0 = __expf(w0 - m), e1 = __expf(w1 - m);
    const float sw0 = e0 / (e0 + e1), sw1 = e1 / (e0 + e1);
    const float c0 = sw0 * 0.5f;

    float4 hv0 = make_float4(0.f, 0.f, 0.f, 0.f);
    float4 hv1 = make_float4(0.f, 0.f, 0.f, 0.f);
    h8acc(hv0, hv1, *(const uint4*)&h[(unsigned)(wid * C_OUT + 8 * cp)]);

    float4 o0, o1;
    o0.x = c0 * (g0.x * inv_g + hg0.x * inv_hg) + sw1 * hv0.x;
    o0.y = c0 * (g0.y * inv_g + hg0.y * inv_hg) + sw1 * hv0.y;
    o0.z = c0 * (g0.z * inv_g + hg0.z * inv_hg) + sw1 * hv0.z;
    o0.w = c0 * (g0.w * inv_g + hg0.w * inv_hg) + sw1 * hv0.w;
    o1.x = c0 * (g1.x * inv_g + hg1.x * inv_hg) + sw1 * hv1.x;
    o1.y = c0 * (g1.y * inv_g + hg1.y * inv_hg) + sw1 * hv1.y;
    o1.z = c0 * (g1.z * inv_g + hg1.z * inv_hg) + sw1 * hv1.z;
    o1.w = c0 * (g1.w * inv_g + hg1.w * inv_hg) + sw1 * hv1.w;
    o0.x = o0.x > 0.f ? o0.x : NEG * o0.x;
    o0.y = o0.y > 0.f ? o0.y : NEG * o0.y;
    o0.z = o0.z > 0.f ? o0.z : NEG * o0.z;
    o0.w = o0.w > 0.f ? o0.w : NEG * o0.w;
    o1.x = o1.x > 0.f ? o1.x : NEG * o1.x;
    o1.y = o1.y > 0.f ? o1.y : NEG * o1.y;
    o1.z = o1.z > 0.f ? o1.z : NEG * o1.z;
    o1.w = o1.w > 0.f ? o1.w : NEG * o1.w;

    if (sub == 0) {
        *(float4*)&out[(unsigned)(wid * C_OUT + 8 * cp)]     = o0;
        *(float4*)&out[(unsigned)(wid * C_OUT + 8 * cp + 4)] = o1;
    }
}

// ---------------------------------------------------------------------------
extern "C" void kernel_launch(void* const* d_in, const int* in_sizes, int n_in,
                              void* d_out, int out_size, void* d_ws, size_t ws_size,
                              hipStream_t stream) {
    const float* x    = (const float*)d_in[0];
    const float* W1   = (const float*)d_in[1];
    const float* b1   = (const float*)d_in[2];
    const float* W2   = (const float*)d_in[3];
    const float* b2   = (const float*)d_in[4];
    const float* w    = (const float*)d_in[5];
    const int*  hg_v  = (const int*)d_in[6];
    const int*  hg_e  = (const int*)d_in[7];
    const int*  g_src = (const int*)d_in[8];
    const int*  g_dst = (const int*)d_in[9];
    float* out = (float*)d_out;

    // ---- workspace layout (~40 MB total) ----
    unsigned* rec_e   = (unsigned*)d_ws;                       // 157*12288 u32
    unsigned* rec_vhg = rec_e   + (size_t)NB_E * ECAP;         // 196*10240 u32
    unsigned* rec_vg  = rec_vhg + (size_t)NB_V * VCAP;         // 196*10240 u32
    // zeroed int region:
    int* bcur_e    = (int*)(rec_vg + (size_t)NB_V * VCAP);     // NB_E
    int* bcur_vhg  = bcur_e   + NB_E;                          // NB_V
    int* bcur_vg   = bcur_vhg + NB_V;                          // NB_V
    // not zeroed:
    int* deg_e     = bcur_vg  + NB_V;                          // N_HGE
    int* deg_vhg   = deg_e    + N_HGE;                         // N_VERTS
    int* deg_vg    = deg_vhg  + N_VERTS;                       // N_VERTS
    int* off_e     = deg_vg   + N_VERTS;                       // N_HGE
    int* off_vhg   = off_e    + N_HGE;                         // N_VERTS
    int* off_vg    = off_vhg  + N_VERTS;                       // N_VERTS
    // fp16 feature arrays — 256B-aligned (round-8 lesson: misaligned h made
    // every 128B gathered row straddle 3 cache lines; FETCH 120->211 MB)
    uintptr_t hp   = ((uintptr_t)(off_vg + N_VERTS) + 255) & ~(uintptr_t)255;
    __half* h      = (__half*)hp;                              // N_VERTS*64 fp16
    __half* e_feat = h + (size_t)N_VERTS * C_OUT;              // N_HGE*64 fp16
    ushort* W1t    = (ushort*)(e_feat + (size_t)N_HGE * C_OUT);// 64 KB fp16
    ushort* W2t    = W1t + C_IN * C_MID;                       // 16 KB fp16

    hipMemsetAsync(bcur_e, 0, (NB_E + 2 * NB_V) * sizeof(int), stream);

    // ---- partition (no count prepass: fixed-capacity buckets) ----
    const int partA_blocks = (N_INC + PAIRS_PER_BLOCK - 1) / PAIRS_PER_BLOCK;
    partitionA_kernel<<<partA_blocks, 256, 0, stream>>>(
        hg_v, hg_e, g_src, g_dst, bcur_e, bcur_vhg, bcur_vg,
        rec_e, rec_vhg, rec_vg);
    partitionB_kernel<<<GRID_B, 256, 0, stream>>>(
        rec_e, rec_vhg, rec_vg, bcur_e, bcur_vhg, bcur_vg,
        deg_e, deg_vhg, deg_vg, off_e, off_vhg, off_vg);

    // ---- weight prep (fp16 transpose) ----
    prep_w_kernel<<<(C_IN * C_MID + C_MID * C_OUT + 255) / 256, 256, 0, stream>>>(
        W1, W2, W1t, W2t);

    // ---- MFMA MLP (fp16, 512-thread blocks, 36 KB LDS -> 4 blocks/CU) ----
    mlp_mfma_kernel<<<(N_VERTS + MBM - 1) / MBM, 512, 0, stream>>>(
        x, W1t, W2t, b1, b2, h);

    // ---- v2e gather ----
    const int ge_blocks = (int)(((size_t)N_HGE * 64 + 255) / 256);
    gather_e_kernel<<<ge_blocks, 256, 0, stream>>>((const int*)rec_e, off_e, deg_e,
                                                   h, e_feat);

    // ---- fused e2v + graph gather + finalize ----
    const int vo_blocks = (int)(((size_t)N_VERTS * 64 + 255) / 256);
    vertex_out_kernel<<<vo_blocks, 256, 0, stream>>>(
        (const int*)rec_vhg, off_vhg, deg_vhg,
        (const int*)rec_vg,  off_vg,  deg_vg,
        e_feat, h, w, out);
}

// Round 11
// 375.647 us; speedup vs baseline: 1.5732x; 1.0405x over previous
//
#include <hip/hip_runtime.h>
#include <hip/hip_bf16.h>
#include <hip/hip_fp16.h>

// Problem constants (fixed by the reference setup)
#define N_VERTS   100000
#define N_HGE     10000
#define N_INC     1600000
#define N_EDGES   1600000
#define C_IN      256
#define C_MID     128
#define C_OUT     64
#define NEG       0.2f

// Radix-partition parameters. Fixed-capacity bucket regions:
//   E-buckets: 64 hyperedges, mean 10240 records, cap 12288
//   V-buckets: 512 vertices,  mean  8192 records, cap 10240
// Caps are statistically unreachable for this fixed input; writes are
// bounds-guarded so even an overflow cannot corrupt memory.
#define EBSHIFT 6
#define NB_E    157              // ceil(10000/64)
#define VBSHIFT 9
#define NB_V    196              // ceil(100000/512)
#define NB_MAX  196
#define ECAP    12288
#define VCAP    10240
#define PAIRS_PER_BLOCK 4096     // 256 threads x 16
#define QP 16

typedef __attribute__((ext_vector_type(8))) _Float16 f16x8;
typedef __attribute__((ext_vector_type(4))) float    f32x4;

// Pack two floats into fp16x2 bits.
__device__ __forceinline__ unsigned packh2(float a, float b) {
    const __half2 h = __float22half2_rn(make_float2(a, b));
    return *(const unsigned*)&h;
}
__device__ __forceinline__ ushort h1bits(float v) {
    const __half x = __float2half_rn(v);
    return *(const ushort*)&x;
}

// Unpack 8 fp16 (as uint4) and accumulate into two float4s.
__device__ __forceinline__ void h8acc(float4& a0, float4& a1, uint4 p) {
    const float2 f0 = __half22float2(*(__half2*)&p.x);
    const float2 f1 = __half22float2(*(__half2*)&p.y);
    const float2 f2 = __half22float2(*(__half2*)&p.z);
    const float2 f3 = __half22float2(*(__half2*)&p.w);
    a0.x += f0.x; a0.y += f0.y; a0.z += f1.x; a0.w += f1.y;
    a1.x += f2.x; a1.y += f2.y; a1.z += f3.x; a1.w += f3.y;
}

// ---------------------------------------------------------------------------
// One-time weight prep: W1/W2 -> fp16, TRANSPOSED to [n][k].
// ---------------------------------------------------------------------------
__global__ __launch_bounds__(256) void
prep_w_kernel(const float* __restrict__ W1, const float* __restrict__ W2,
              ushort* __restrict__ W1t, ushort* __restrict__ W2t) {
    const int idx = blockIdx.x * 256 + threadIdx.x;
    if (idx < C_IN * C_MID) {                       // W1t[n][k], n<128,k<256
        const int n = idx >> 8, k = idx & 255;
        W1t[idx] = h1bits(W1[k * C_MID + n]);
    } else {
        const int j = idx - C_IN * C_MID;
        if (j < C_MID * C_OUT) {                    // W2t[n][k], n<64,k<128
            const int n = j >> 7, k = j & 127;
            W2t[j] = h1bits(W2[k * C_OUT + n]);
        }
    }
}

// ---------------------------------------------------------------------------
// MFMA MLP, fp16 (round-10 proven): h = leaky_relu(x @ W1 + b1) @ W2 + b2.
// 512 threads, 8 waves 2x4, 36 KB LDS -> 4 blocks/CU.
// Fragment maps [m89]: A: row=l&15, k=(l>>4)*8+e; B: col=l&15, same k;
// C/D: col=l&15, row=(l>>4)*4+reg.
// ---------------------------------------------------------------------------
#define MBM 128
__global__ __launch_bounds__(512) void
mlp_mfma_kernel(const float* __restrict__ x,
                const ushort* __restrict__ W1t, const ushort* __restrict__ W2t,
                const float* __restrict__ b1, const float* __restrict__ b2,
                __half* __restrict__ h) {
    // union LDS: phase1 = xs/ws [128][72]; phase2 = mid [128][136]  (36 KB)
    __shared__ ushort buf[18432];
    ushort* xs  = buf;            // [128][72]
    ushort* ws  = buf + 9216;     // [128][72]
    ushort* mid = buf;            // [128][136]

    const int t    = threadIdx.x;
    const int lane = t & 63;
    const int wid  = t >> 6;                       // 0..7
    const int wr   = wid >> 2, wc = wid & 3;       // 2x4 wave grid
    const int v0   = blockIdx.x * MBM;
    const int rem  = N_VERTS - v0;                 // <128 only in last block
    const int l15  = lane & 15;
    const int lg   = lane >> 4;                    // 0..3

    f32x4 acc[4][2];
#pragma unroll
    for (int i = 0; i < 4; ++i) { acc[i][0] = (f32x4)0.f; acc[i][1] = (f32x4)0.f; }

    // ---- layer 1: K tiled by 64 (4 tiles), fp16 staged in LDS ----
    for (int kt = 0; kt < 4; ++kt) {
        __syncthreads();
#pragma unroll
        for (int it = 0; it < 4; ++it) {           // x tile: 2048 float4
            const int idx = it * 512 + t;
            const int row = idx >> 4;
            const int c4  = (idx & 15) * 4;
            float4 v = make_float4(0.f, 0.f, 0.f, 0.f);
            if (row < rem)
                v = *(const float4*)&x[(size_t)(v0 + row) * C_IN + kt * 64 + c4];
            uint2 p;
            p.x = packh2(v.x, v.y);
            p.y = packh2(v.z, v.w);
            *(uint2*)&xs[row * 72 + c4] = p;
        }
#pragma unroll
        for (int it = 0; it < 4; ++it) {           // W1t tile (fp16 in global)
            const int idx = it * 512 + t;
            const int n  = idx >> 4;
            const int c4 = (idx & 15) * 4;
            *(uint2*)&ws[n * 72 + c4] = *(const uint2*)&W1t[n * 256 + kt * 64 + c4];
        }
        __syncthreads();

#pragma unroll
        for (int ks = 0; ks < 2; ++ks) {
            const int k0 = ks * 32 + lg * 8;
            f16x8 a[4], b[2];
#pragma unroll
            for (int mf = 0; mf < 4; ++mf)
                a[mf] = *(const f16x8*)&xs[(wr * 64 + mf * 16 + l15) * 72 + k0];
#pragma unroll
            for (int nf = 0; nf < 2; ++nf)
                b[nf] = *(const f16x8*)&ws[(wc * 32 + nf * 16 + l15) * 72 + k0];
#pragma unroll
            for (int mf = 0; mf < 4; ++mf)
#pragma unroll
                for (int nf = 0; nf < 2; ++nf)
                    acc[mf][nf] = __builtin_amdgcn_mfma_f32_16x16x32_f16(
                        a[mf], b[nf], acc[mf][nf], 0, 0, 0);
        }
    }
    __syncthreads();

    // ---- bias + leaky, fp16 write mid[m][k] (k = layer1 col) ----
#pragma unroll
    for (int nf = 0; nf < 2; ++nf) {
        const int col = wc * 32 + nf * 16 + l15;
        const float bias = b1[col];
#pragma unroll
        for (int mf = 0; mf < 4; ++mf)
#pragma unroll
            for (int j = 0; j < 4; ++j) {
                const int r = wr * 64 + mf * 16 + lg * 4 + j;
                float v = acc[mf][nf][j] + bias;
                v = v > 0.f ? v : NEG * v;
                mid[r * 136 + col] = h1bits(v);
            }
    }
    __syncthreads();

    // ---- layer 2: K = 128, W2 fragments straight from global (L1-resident) ----
    f32x4 acc2[4];
#pragma unroll
    for (int i = 0; i < 4; ++i) acc2[i] = (f32x4)0.f;

#pragma unroll
    for (int ks2 = 0; ks2 < 4; ++ks2) {
        const int k0 = ks2 * 32 + lg * 8;
        f16x8 a[4];
#pragma unroll
        for (int mf = 0; mf < 4; ++mf)
            a[mf] = *(const f16x8*)&mid[(wr * 64 + mf * 16 + l15) * 136 + k0];
        const f16x8 b = *(const f16x8*)&W2t[(wc * 16 + l15) * 128 + k0];
#pragma unroll
        for (int mf = 0; mf < 4; ++mf)
            acc2[mf] = __builtin_amdgcn_mfma_f32_16x16x32_f16(
                a[mf], b, acc2[mf], 0, 0, 0);
    }

    // ---- store h as fp16 ----
    {
        const int col = wc * 16 + l15;
        const float b2c = b2[col];
#pragma unroll
        for (int mf = 0; mf < 4; ++mf)
#pragma unroll
            for (int j = 0; j < 4; ++j) {
                const int r = wr * 64 + mf * 16 + lg * 4 + j;
                if (r < rem)
                    h[(size_t)(v0 + r) * C_OUT + col] =
                        __float2half_rn(acc2[mf][j] + b2c);
            }
    }
}

// ---------------------------------------------------------------------------
// Phase A: radix partition into fixed-capacity bucket regions.
// Records packed to u32: (dst-in-bucket << 17) | payload.
// LDS-staged: rank per bucket in LDS, reorder, then stream out coalesced.
// ---------------------------------------------------------------------------
__global__ __launch_bounds__(256) void
partitionA_kernel(const int* __restrict__ hg_v, const int* __restrict__ hg_e,
                  const int* __restrict__ g_src, const int* __restrict__ g_dst,
                  int* __restrict__ bcur_e, int* __restrict__ bcur_vhg,
                  int* __restrict__ bcur_vg,
                  unsigned* __restrict__ rec_e, unsigned* __restrict__ rec_vhg,
                  unsigned* __restrict__ rec_vg) {
    __shared__ int hist[NB_MAX];
    __shared__ int lstart[NB_MAX];
    __shared__ int gb[NB_MAX];
    __shared__ int sscan[256];
    __shared__ unsigned lbuf[PAIRS_PER_BLOCK];        // 16 KB
    __shared__ unsigned char bkt8[PAIRS_PER_BLOCK];   // 4 KB
    const int t    = threadIdx.x;
    const int i0   = blockIdx.x * PAIRS_PER_BLOCK;
    const int vcnt = min(PAIRS_PER_BLOCK, N_INC - i0);

    for (int table = 0; table < 3; ++table) {
        const int *dsts, *pays; int *bcur; unsigned* rec; int shift, nb, cap;
        if (table == 0)      { dsts = hg_e;  pays = hg_v;  bcur = bcur_e;
                               rec = rec_e;   shift = EBSHIFT; nb = NB_E; cap = ECAP; }
        else if (table == 1) { dsts = hg_v;  pays = hg_e;  bcur = bcur_vhg;
                               rec = rec_vhg; shift = VBSHIFT; nb = NB_V; cap = VCAP; }
        else                 { dsts = g_dst; pays = g_src; bcur = bcur_vg;
                               rec = rec_vg;  shift = VBSHIFT; nb = NB_V; cap = VCAP; }
        const int dmask = (1 << shift) - 1;

        if (t < nb) hist[t] = 0;
        __syncthreads();

        unsigned pk[QP]; int bk[QP], rk[QP];
#pragma unroll
        for (int q = 0; q < QP; ++q) {
            const int i = i0 + t + q * 256;
            if (i < N_INC) {
                const int d = dsts[i];
                const int p = pays[i];
                bk[q] = d >> shift;
                pk[q] = ((unsigned)(d & dmask) << 17) | (unsigned)p;
                rk[q] = atomicAdd(&hist[bk[q]], 1);
            } else bk[q] = -1;
        }
        __syncthreads();

        // exclusive scan of hist -> lstart; reserve global runs via bcur
        {
            const int own = (t < nb) ? hist[t] : 0;
            sscan[t] = own;
            __syncthreads();
            for (int d2 = 1; d2 < 256; d2 <<= 1) {
                int v = (t >= d2) ? sscan[t - d2] : 0;
                __syncthreads();
                sscan[t] += v;
                __syncthreads();
            }
            if (t < nb) {
                lstart[t] = sscan[t] - own;
                gb[t] = own ? atomicAdd(&bcur[t], own) : 0;
            }
        }
        __syncthreads();

        // reorder into LDS, bucket-sorted
#pragma unroll
        for (int q = 0; q < QP; ++q) {
            if (bk[q] >= 0) {
                const int lp = lstart[bk[q]] + rk[q];
                lbuf[lp] = pk[q];
                bkt8[lp] = (unsigned char)bk[q];
            }
        }
        __syncthreads();

        // stream out: bucket-run coalescing
        for (int i = t; i < vcnt; i += 256) {
            const int b  = bkt8[i];
            const int pos = gb[b] + (i - lstart[b]);
            if (pos < cap)                         // statistically always true
                rec[(size_t)b * cap + pos] = lbuf[i];
        }
        __syncthreads();   // LDS reused next table
    }
}

// ---------------------------------------------------------------------------
// Phase B: per-bucket CSR derivation + dense slot build in LDS.
// Overwrites the record region IN-PLACE as the final slot array.
// ---------------------------------------------------------------------------
#define GRID_B (NB_E + 2 * NB_V)
__global__ __launch_bounds__(256) void
partitionB_kernel(unsigned* __restrict__ rec_e, unsigned* __restrict__ rec_vhg,
                  unsigned* __restrict__ rec_vg,
                  const int* __restrict__ bcur_e, const int* __restrict__ bcur_vhg,
                  const int* __restrict__ bcur_vg,
                  int* __restrict__ deg_e, int* __restrict__ deg_vhg,
                  int* __restrict__ deg_vg,
                  int* __restrict__ off_e, int* __restrict__ off_vhg,
                  int* __restrict__ off_vg) {
    __shared__ int slotbuf[ECAP];         // 48 KB (ECAP >= VCAP)
    __shared__ int cnt_l[1 << VBSHIFT];   // 2 KB
    __shared__ int cur_l[1 << VBSHIFT];   // 2 KB
    __shared__ int part[256];             // 1 KB

    int blk = blockIdx.x;
    unsigned* rec; const int* bcur; int* deg; int* off;
    int b, shift, ndst, cap;
    if (blk < NB_E) {
        rec = rec_e; bcur = bcur_e; deg = deg_e; off = off_e;
        shift = EBSHIFT; ndst = N_HGE; cap = ECAP; b = blk;
    } else if (blk < NB_E + NB_V) {
        rec = rec_vhg; bcur = bcur_vhg; deg = deg_vhg; off = off_vhg;
        shift = VBSHIFT; ndst = N_VERTS; cap = VCAP; b = blk - NB_E;
    } else {
        rec = rec_vg; bcur = bcur_vg; deg = deg_vg; off = off_vg;
        shift = VBSHIFT; ndst = N_VERTS; cap = VCAP; b = blk - NB_E - NB_V;
    }
    const int t    = threadIdx.x;
    const int dlo  = b << shift;
    const int nd   = 1 << shift;
    const int ndc  = min(nd, ndst - dlo);
    const int bs   = b * cap;
    const int bcnt = min(bcur[b], cap);

    // pass 1: per-dst counts in LDS
    for (int j = t; j < nd; j += 256) cnt_l[j] = 0;
    __syncthreads();
    for (int i = t; i < bcnt; i += 256)
        atomicAdd(&cnt_l[rec[bs + i] >> 17], 1);
    __syncthreads();

    // exclusive scan over nd (64 or 512) counts with 256 threads
    const int chunk = (nd + 255) / 256;     // 1 or 2
    const int lo = t * chunk;
    const int hi = min(lo + chunk, nd);
    int s = 0;
    for (int j = lo; j < hi; ++j) s += cnt_l[j];
    part[t] = s;
    __syncthreads();
    for (int d = 1; d < 256; d <<= 1) {
        int v = (t >= d) ? part[t - d] : 0;
        __syncthreads();
        part[t] += v;
        __syncthreads();
    }
    int run = (t > 0) ? part[t - 1] : 0;
    for (int j = lo; j < hi; ++j) { cur_l[j] = run; run += cnt_l[j]; }
    __syncthreads();

    // emit CSR (deg + global off into the padded slot layout), coalesced
    for (int j = t; j < ndc; j += 256) {
        deg[dlo + j] = cnt_l[j];
        off[dlo + j] = bs + cur_l[j];
    }
    __syncthreads();   // cur_l becomes the scatter cursor below

    // pass 2: scatter payloads into LDS, then overwrite rec in-place as slots
    for (int i = t; i < bcnt; i += 256) {
        const unsigned r = rec[bs + i];
        const int lpos = atomicAdd(&cur_l[r >> 17], 1);
        slotbuf[lpos] = (int)(r & 0x1FFFFu);
    }
    __syncthreads();
    for (int i = t; i < bcnt; i += 256)
        rec[bs + i] = (unsigned)slotbuf[i];
}

// ---------------------------------------------------------------------------
// v2e gather: 8 hyperedges per wave, one 8-lane subgroup each. Lane owns a
// fixed channel-octet (16B uint4) of its edge; slots accumulate SERIALLY —
// no cross-lane reduction at all (round-10 lesson: xreduce8 was >half the
// VALU work at small mean degree).
// ---------------------------------------------------------------------------
__global__ void gather_e_kernel(const int* __restrict__ slot, const int* __restrict__ off,
                                const int* __restrict__ deg, const __half* __restrict__ h,
                                __half* __restrict__ e_feat) {
    const int wv   = (blockIdx.x * blockDim.x + threadIdx.x) >> 6;
    const int lane = threadIdx.x & 63;
    const int sub  = lane >> 3;      // edge-in-wave
    const int cp   = lane & 7;       // channel octet
    const int eid  = wv * 8 + sub;
    if (eid >= N_HGE) return;
    const int n    = deg[eid];
    const int base = off[eid];

    float4 a0 = make_float4(0.f, 0.f, 0.f, 0.f);
    float4 a1 = make_float4(0.f, 0.f, 0.f, 0.f);
    int j = 0;
    for (; j + 4 <= n; j += 4) {
        const int s0 = slot[base + j + 0];
        const int s1 = slot[base + j + 1];
        const int s2 = slot[base + j + 2];
        const int s3 = slot[base + j + 3];
        const uint4 p0 = *(const uint4*)&h[(unsigned)(s0 * C_OUT + 8 * cp)];
        const uint4 p1 = *(const uint4*)&h[(unsigned)(s1 * C_OUT + 8 * cp)];
        const uint4 p2 = *(const uint4*)&h[(unsigned)(s2 * C_OUT + 8 * cp)];
        const uint4 p3 = *(const uint4*)&h[(unsigned)(s3 * C_OUT + 8 * cp)];
        h8acc(a0, a1, p0); h8acc(a0, a1, p1);
        h8acc(a0, a1, p2); h8acc(a0, a1, p3);
    }
    for (; j < n; ++j) {
        const int s = slot[base + j];
        h8acc(a0, a1, *(const uint4*)&h[(unsigned)(s * C_OUT + 8 * cp)]);
    }
    const float inv = 1.f / fmaxf((float)n, 1.f);
    const __half2 r0 = __float22half2_rn(make_float2(a0.x * inv, a0.y * inv));
    const __half2 r1 = __float22half2_rn(make_float2(a0.z * inv, a0.w * inv));
    const __half2 r2 = __float22half2_rn(make_float2(a1.x * inv, a1.y * inv));
    const __half2 r3 = __float22half2_rn(make_float2(a1.z * inv, a1.w * inv));
    uint4 pk;
    pk.x = *(const unsigned*)&r0;
    pk.y = *(const unsigned*)&r1;
    pk.z = *(const unsigned*)&r2;
    pk.w = *(const unsigned*)&r3;
    *(uint4*)&e_feat[(unsigned)(eid * C_OUT + 8 * cp)] = pk;
}

// ---------------------------------------------------------------------------
// Fused per-vertex epilogue: 8 vertices per wave, one 8-lane subgroup each,
// lane owns a channel-octet; serial slot accumulation, NO reductions.
// N_VERTS = 100000 = 8 * 12500 -> every wave fully populated.
// ---------------------------------------------------------------------------
__global__ void vertex_out_kernel(const int* __restrict__ slot_vhg,
                                  const int* __restrict__ off_vhg,
                                  const int* __restrict__ deg_vhg,
                                  const int* __restrict__ slot_vg,
                                  const int* __restrict__ off_vg,
                                  const int* __restrict__ deg_vg,
                                  const __half* __restrict__ e_feat,
                                  const __half* __restrict__ h,
                                  const float* __restrict__ w,
                                  float* __restrict__ out) {
    const int wv   = (blockIdx.x * blockDim.x + threadIdx.x) >> 6;
    const int lane = threadIdx.x & 63;
    const int sub  = lane >> 3;      // vertex-in-wave
    const int cp   = lane & 7;       // channel octet
    const int vid  = wv * 8 + sub;
    if (vid >= N_VERTS) return;

    float4 hg0 = make_float4(0.f, 0.f, 0.f, 0.f);
    float4 hg1 = make_float4(0.f, 0.f, 0.f, 0.f);
    float inv_hg;
    {
        const int n = deg_vhg[vid];
        const int base = off_vhg[vid];
        int j = 0;
        for (; j + 4 <= n; j += 4) {
            const int s0 = slot_vhg[base + j + 0];
            const int s1 = slot_vhg[base + j + 1];
            const int s2 = slot_vhg[base + j + 2];
            const int s3 = slot_vhg[base + j + 3];
            const uint4 p0 = *(const uint4*)&e_feat[(unsigned)(s0 * C_OUT + 8 * cp)];
            const uint4 p1 = *(const uint4*)&e_feat[(unsigned)(s1 * C_OUT + 8 * cp)];
            const uint4 p2 = *(const uint4*)&e_feat[(unsigned)(s2 * C_OUT + 8 * cp)];
            const uint4 p3 = *(const uint4*)&e_feat[(unsigned)(s3 * C_OUT + 8 * cp)];
            h8acc(hg0, hg1, p0); h8acc(hg0, hg1, p1);
            h8acc(hg0, hg1, p2); h8acc(hg0, hg1, p3);
        }
        for (; j < n; ++j) {
            const int s = slot_vhg[base + j];
            h8acc(hg0, hg1, *(const uint4*)&e_feat[(unsigned)(s * C_OUT + 8 * cp)]);
        }
        inv_hg = 1.f / fmaxf((float)n, 1.f);
    }

    float4 g0 = make_float4(0.f, 0.f, 0.f, 0.f);
    float4 g1 = make_float4(0.f, 0.f, 0.f, 0.f);
    float inv_g;
    {
        const int n = deg_vg[vid];
        const int base = off_vg[vid];
        int j = 0;
        for (; j + 4 <= n; j += 4) {
            const int s0 = slot_vg[base + j + 0];
            const int s1 = slot_vg[base + j + 1];
            const int s2 = slot_vg[base + j + 2];
            const int s3 = slot_vg[base + j + 3];
            const uint4 p0 = *(const uint4*)&h[(unsigned)(s0 * C_OUT + 8 * cp)];
            const uint4 p1 = *(const uint4*)&h[(unsigned)(s1 * C_OUT + 8 * cp)];
            const uint4 p2 = *(const uint4*)&h[(unsigned)(s2 * C_OUT + 8 * cp)];
            const uint4 p3 = *(const uint4*)&h[(unsigned)(s3 * C_OUT + 8 * cp)];
            h8acc(g0, g1, p0); h8acc(g0, g1, p1);
            h8acc(g0, g1, p2); h8acc(g0, g1, p3);
        }
        for (; j < n; ++j) {
            const int s = slot_vg[base + j];
            h8acc(g0, g1, *(const uint4*)&h[(unsigned)(s * C_OUT + 8 * cp)]);
        }
        inv_g = 1.f / fmaxf((float)n, 1.f);
    }

    const float w0 = w[0], w1 = w[1];
    const float m  = fmaxf(w0, w1);
    const float e0 = __expf(w0 - m), e1 = __expf(w1 - m);
    const float sw0 = e0 / (e0 + e1), sw1 = e1 / (e0 + e1);
    const float c0 = sw0 * 0.5f;

    float4 hv0 = make_float4(0.f, 0.f, 0.f, 0.f);
    float4 hv1 = make_float4(0.f, 0.f, 0.f, 0.f);
    h8acc(hv0, hv1, *(const uint4*)&h[(unsigned)(vid * C_OUT + 8 * cp)]);

    float4 o0, o1;
    o0.x = c0 * (g0.x * inv_g + hg0.x * inv_hg) + sw1 * hv0.x;
    o0.y = c0 * (g0.y * inv_g + hg0.y * inv_hg) + sw1 * hv0.y;
    o0.z = c0 * (g0.z * inv_g + hg0.z * inv_hg) + sw1 * hv0.z;
    o0.w = c0 * (g0.w * inv_g + hg0.w * inv_hg) + sw1 * hv0.w;
    o1.x = c0 * (g1.x * inv_g + hg1.x * inv_hg) + sw1 * hv1.x;
    o1.y = c0 * (g1.y * inv_g + hg1.y * inv_hg) + sw1 * hv1.y;
    o1.z = c0 * (g1.z * inv_g + hg1.z * inv_hg) + sw1 * hv1.z;
    o1.w = c0 * (g1.w * inv_g + hg1.w * inv_hg) + sw1 * hv1.w;
    o0.x = o0.x > 0.f ? o0.x : NEG * o0.x;
    o0.y = o0.y > 0.f ? o0.y : NEG * o0.y;
    o0.z = o0.z > 0.f ? o0.z : NEG * o0.z;
    o0.w = o0.w > 0.f ? o0.w : NEG * o0.w;
    o1.x = o1.x > 0.f ? o1.x : NEG * o1.x;
    o1.y = o1.y > 0.f ? o1.y : NEG * o1.y;
    o1.z = o1.z > 0.f ? o1.z : NEG * o1.z;
    o1.w = o1.w > 0.f ? o1.w : NEG * o1.w;

    *(float4*)&out[(unsigned)(vid * C_OUT + 8 * cp)]     = o0;
    *(float4*)&out[(unsigned)(vid * C_OUT + 8 * cp + 4)] = o1;
}

// ---------------------------------------------------------------------------
extern "C" void kernel_launch(void* const* d_in, const int* in_sizes, int n_in,
                              void* d_out, int out_size, void* d_ws, size_t ws_size,
                              hipStream_t stream) {
    const float* x    = (const float*)d_in[0];
    const float* W1   = (const float*)d_in[1];
    const float* b1   = (const float*)d_in[2];
    const float* W2   = (const float*)d_in[3];
    const float* b2   = (const float*)d_in[4];
    const float* w    = (const float*)d_in[5];
    const int*  hg_v  = (const int*)d_in[6];
    const int*  hg_e  = (const int*)d_in[7];
    const int*  g_src = (const int*)d_in[8];
    const int*  g_dst = (const int*)d_in[9];
    float* out = (float*)d_out;

    // ---- workspace layout (~40 MB total) ----
    unsigned* rec_e   = (unsigned*)d_ws;                       // 157*12288 u32
    unsigned* rec_vhg = rec_e   + (size_t)NB_E * ECAP;         // 196*10240 u32
    unsigned* rec_vg  = rec_vhg + (size_t)NB_V * VCAP;         // 196*10240 u32
    // zeroed int region:
    int* bcur_e    = (int*)(rec_vg + (size_t)NB_V * VCAP);     // NB_E
    int* bcur_vhg  = bcur_e   + NB_E;                          // NB_V
    int* bcur_vg   = bcur_vhg + NB_V;                          // NB_V
    // not zeroed:
    int* deg_e     = bcur_vg  + NB_V;                          // N_HGE
    int* deg_vhg   = deg_e    + N_HGE;                         // N_VERTS
    int* deg_vg    = deg_vhg  + N_VERTS;                       // N_VERTS
    int* off_e     = deg_vg   + N_VERTS;                       // N_HGE
    int* off_vhg   = off_e    + N_HGE;                         // N_VERTS
    int* off_vg    = off_vhg  + N_VERTS;                       // N_VERTS
    // fp16 feature arrays — 256B-aligned (round-8 lesson: misaligned h made
    // every 128B gathered row straddle 3 cache lines; FETCH 120->211 MB)
    uintptr_t hp   = ((uintptr_t)(off_vg + N_VERTS) + 255) & ~(uintptr_t)255;
    __half* h      = (__half*)hp;                              // N_VERTS*64 fp16
    __half* e_feat = h + (size_t)N_VERTS * C_OUT;              // N_HGE*64 fp16
    ushort* W1t    = (ushort*)(e_feat + (size_t)N_HGE * C_OUT);// 64 KB fp16
    ushort* W2t    = W1t + C_IN * C_MID;                       // 16 KB fp16

    hipMemsetAsync(bcur_e, 0, (NB_E + 2 * NB_V) * sizeof(int), stream);

    // ---- partition (no count prepass: fixed-capacity buckets) ----
    const int partA_blocks = (N_INC + PAIRS_PER_BLOCK - 1) / PAIRS_PER_BLOCK;
    partitionA_kernel<<<partA_blocks, 256, 0, stream>>>(
        hg_v, hg_e, g_src, g_dst, bcur_e, bcur_vhg, bcur_vg,
        rec_e, rec_vhg, rec_vg);
    partitionB_kernel<<<GRID_B, 256, 0, stream>>>(
        rec_e, rec_vhg, rec_vg, bcur_e, bcur_vhg, bcur_vg,
        deg_e, deg_vhg, deg_vg, off_e, off_vhg, off_vg);

    // ---- weight prep (fp16 transpose) ----
    prep_w_kernel<<<(C_IN * C_MID + C_MID * C_OUT + 255) / 256, 256, 0, stream>>>(
        W1, W2, W1t, W2t);

    // ---- MFMA MLP (fp16, 512-thread blocks, 36 KB LDS -> 4 blocks/CU) ----
    mlp_mfma_kernel<<<(N_VERTS + MBM - 1) / MBM, 512, 0, stream>>>(
        x, W1t, W2t, b1, b2, h);

    // ---- v2e gather: 8 edges/wave ----
    const int ge_threads = ((N_HGE + 7) / 8) * 64;
    gather_e_kernel<<<(ge_threads + 255) / 256, 256, 0, stream>>>(
        (const int*)rec_e, off_e, deg_e, h, e_feat);

    // ---- fused e2v + graph gather + finalize: 8 vertices/wave ----
    const int vo_threads = ((N_VERTS + 7) / 8) * 64;
    vertex_out_kernel<<<(vo_threads + 255) / 256, 256, 0, stream>>>(
        (const int*)rec_vhg, off_vhg, deg_vhg,
        (const int*)rec_vg,  off_vg,  deg_vg,
        e_feat, h, w, out);
}